// Round 3
// baseline (703.197 us; speedup 1.0000x reference)
//
#include <hip/hip_runtime.h>
#include <hip/hip_bf16.h>

// ---------------------------------------------------------------------------
// MultiHeadAttention block on MI355X (gfx950). Input dtype (f32 vs bf16) is
// detected ON DEVICE (round-2 theory: persistent NaN = f32 inputs read as
// bf16; even shorts of f32 data are random mantissa bits, ~0.4% decode as
// bf16 NaN). Internal pipeline is bf16 MFMA with fp32 accumulate.
//   xn=LN(x), yn=LN(y); Q=xn@Wq, K=yn@Wk, V=yn@Wv (weights pre-packed [H*D,C])
//   A=softmax(QK^T/8) over all t; triu(k=1) mask applied AFTER softmax
//   O=A@V; x_out = x + O@li1_w + li1_b
//   out = x_out + gelu_exact(LN3(x_out)@li2_w+li2_b)@li3_w + li3_b
// Workspace (88MB + 32KB):
//   [0,8M) xn/hn  [8,16M) yn/O  [16,24M) WqT,WkT,WvT,li1T  [24,32M) li2T
//   [32,40M) li3T  [40,48M) xout  [48,80M) Q,K,V -> h2  [80,88M) xc
//   [88M+0) dtype flag, [88M+4K..) canonical biases
// ---------------------------------------------------------------------------

typedef __hip_bfloat16 bf16;
typedef __attribute__((ext_vector_type(8))) short  s16x8;
typedef __attribute__((ext_vector_type(4))) short  s16x4;
typedef __attribute__((ext_vector_type(4))) float  f32x4;
typedef __attribute__((ext_vector_type(4))) _Float16 h16x4;

__device__ __forceinline__ float bfbits2f(short s) {
    return __uint_as_float(((unsigned)(unsigned short)s) << 16);
}
__device__ __forceinline__ float load_in(const void* p, size_t i, int f32) {
    return f32 ? ((const float*)p)[i] : bfbits2f(((const short*)p)[i]);
}

// ------------------------- dtype detection ---------------------------------
// Even shorts of bf16 data: valid bf16 values (exp in [113,142] for N(0,1)).
// Even shorts of f32 data: low mantissa bits -> exp field uniform (~12% hit).
__global__ __launch_bounds__(256)
void detect_dtype(const short* __restrict__ x, int* __restrict__ flag)
{
    const int tid = threadIdx.x;
    int cnt = 0;
#pragma unroll
    for (int e = 0; e < 16; e++) {
        int idx = (tid * 16 + e) * 2;            // even shorts only
        int ex  = (x[idx] >> 7) & 0xFF;
        if (ex >= 113 && ex <= 142) cnt++;
    }
#pragma unroll
    for (int off = 1; off < 64; off <<= 1) cnt += __shfl_xor(cnt, off, 64);
    __shared__ int sh[4];
    if ((tid & 63) == 0) sh[tid >> 6] = cnt;
    __syncthreads();
    if (tid == 0) {
        int tot = sh[0] + sh[1] + sh[2] + sh[3];  // bf16: ~4096, f32: ~480
        flag[0] = (tot < 2458) ? 1 : 0;           // 1 == inputs are float32
    }
}

// --------------------- flag-aware conversion / repack ----------------------
__global__ __launch_bounds__(256)
void conv_to_bf16(const void* __restrict__ in, bf16* __restrict__ out, int n,
                  const int* __restrict__ flag)
{
    int i = blockIdx.x * 256 + threadIdx.x;
    if (i >= n) return;
    out[i] = __float2bfloat16(load_in(in, i, flag[0]));
}

// Wq [H,C,D] -> WqT [H*D, C]
__global__ __launch_bounds__(256)
void pack_qkv_w(const void* __restrict__ in, bf16* __restrict__ out,
                const int* __restrict__ flag)
{
    const int f32 = flag[0];
    int oi = blockIdx.x * 256 + threadIdx.x;   // H*D*C = 1M
    int c  = oi & 1023;
    int n  = oi >> 10;
    int h  = n >> 6, d = n & 63;
    out[oi] = __float2bfloat16(load_in(in, ((size_t)h * 1024 + c) * 64 + d, f32));
}

// in [R,Cc] -> out [Cc,R]
__global__ __launch_bounds__(256)
void transpose2d(const void* __restrict__ in, bf16* __restrict__ out,
                 int R, int Cc, const int* __restrict__ flag)
{
    const int f32 = flag[0];
    int oi = blockIdx.x * 256 + threadIdx.x;   // R*Cc
    int r  = oi % R;
    int c  = oi / R;
    out[oi] = __float2bfloat16(load_in(in, (size_t)r * Cc + c, f32));
}

// ------------------------------- LayerNorm ---------------------------------
// one row (C=1024) per 256-thread block.
// xf32sel: -1 -> x is always bf16 (internal buffer); 0/1 irrelevant then.
//          otherwise x dtype follows flag. w/b always follow flag (raw inputs).
__global__ __launch_bounds__(256)
void ln_kernel(const void* __restrict__ x, const void* __restrict__ w,
               const void* __restrict__ bv, bf16* __restrict__ out,
               const int* __restrict__ flag, int x_is_bf16)
{
    const int f32  = flag[0];
    const int xf32 = x_is_bf16 ? 0 : f32;
    const int row  = blockIdx.x;
    const int tid  = threadIdx.x;
    const int lane = tid & 63;
    const int wave = tid >> 6;
    const size_t base = (size_t)row * 1024 + tid * 4;

    float v[4];
    float sum = 0.f, ss = 0.f;
#pragma unroll
    for (int e = 0; e < 4; e++) {
        v[e] = load_in(x, base + e, xf32);
        sum += v[e]; ss += v[e] * v[e];
    }
#pragma unroll
    for (int off = 1; off < 64; off <<= 1) {
        sum += __shfl_xor(sum, off, 64);
        ss  += __shfl_xor(ss,  off, 64);
    }
    __shared__ float sh1[4], sh2[4];
    if (lane == 0) { sh1[wave] = sum; sh2[wave] = ss; }
    __syncthreads();
    float t1 = sh1[0] + sh1[1] + sh1[2] + sh1[3];
    float t2 = sh2[0] + sh2[1] + sh2[2] + sh2[3];
    float mu   = t1 * (1.f / 1024.f);
    float var  = t2 * (1.f / 1024.f) - mu * mu;
    float rstd = rsqrtf(var + 1e-5f);

#pragma unroll
    for (int e = 0; e < 4; e++) {
        float ov = (v[e] - mu) * rstd * load_in(w, tid * 4 + e, f32)
                 + load_in(bv, tid * 4 + e, f32);
        out[base + e] = __float2bfloat16(ov);
    }
}

// ------------------------------ GEMM (B^T) ---------------------------------
// C[M,N] = A[M,K] @ Bt[N,K]^T, bf16 in, fp32 acc; bias/gelu/residual epilogue.
// 256 thr = 4 waves (2x2), tile 128x128, BK=32, wave = 64x64 = 4x4 MFMA.
// final_out: if set and *dflag, store float32 to C (harness f32 output).
__global__ __launch_bounds__(256)
void gemm_bt(const bf16* __restrict__ A, const bf16* __restrict__ Bt,
             const bf16* __restrict__ bias, const bf16* __restrict__ res,
             void* __restrict__ C, int M, int N, int K, int act,
             const int* __restrict__ dflag, int final_out)
{
    __shared__ alignas(16) short As[128][40];   // pad 40: 80B rows, 2-way only
    __shared__ alignas(16) short Bs[128][40];

    const int f32out = final_out ? dflag[0] : 0;
    const int tid  = threadIdx.x;
    const int lane = tid & 63;
    const int wave = tid >> 6;
    const int q    = lane >> 4;
    const int l15  = lane & 15;
    const int wm   = (wave >> 1) * 64;
    const int wn   = (wave & 1) * 64;
    const int bm   = blockIdx.x * 128;
    const int bn   = blockIdx.y * 128;

    const int lrow = tid >> 2;        // 0..63
    const int lcol = (tid & 3) * 8;   // 0,8,16,24

    f32x4 acc[4][4] = {};

    for (int k0 = 0; k0 < K; k0 += 32) {
        const short* Ap = (const short*)A  + (size_t)(bm + lrow) * K + k0 + lcol;
        const short* Bp = (const short*)Bt + (size_t)(bn + lrow) * K + k0 + lcol;
        s16x8 a0 = *(const s16x8*)Ap;
        s16x8 a1 = *(const s16x8*)(Ap + (size_t)64 * K);
        s16x8 b0 = *(const s16x8*)Bp;
        s16x8 b1 = *(const s16x8*)(Bp + (size_t)64 * K);
        __syncthreads();
        *(s16x8*)&As[lrow][lcol]      = a0;
        *(s16x8*)&As[lrow + 64][lcol] = a1;
        *(s16x8*)&Bs[lrow][lcol]      = b0;
        *(s16x8*)&Bs[lrow + 64][lcol] = b1;
        __syncthreads();

        s16x8 af[4], bfrag[4];
#pragma unroll
        for (int i = 0; i < 4; i++) af[i]    = *(const s16x8*)&As[wm + i * 16 + l15][q * 8];
#pragma unroll
        for (int j = 0; j < 4; j++) bfrag[j] = *(const s16x8*)&Bs[wn + j * 16 + l15][q * 8];
#pragma unroll
        for (int i = 0; i < 4; i++)
#pragma unroll
            for (int j = 0; j < 4; j++)
                acc[i][j] = __builtin_amdgcn_mfma_f32_16x16x32_bf16(af[i], bfrag[j], acc[i][j], 0, 0, 0);
    }

    // epilogue: C/D layout col=lane&15, row=quad*4+reg
#pragma unroll
    for (int i = 0; i < 4; i++) {
#pragma unroll
        for (int j = 0; j < 4; j++) {
            int n = bn + wn + j * 16 + l15;
            float bvv = bias ? __bfloat162float(bias[n]) : 0.f;
#pragma unroll
            for (int r = 0; r < 4; r++) {
                int m = bm + wm + i * 16 + q * 4 + r;
                float v = acc[i][j][r] + bvv;
                if (act) v = 0.5f * v * (1.f + erff(v * 0.70710678118f));
                if (res) v += __bfloat162float(res[(size_t)m * N + n]);
                size_t idx = (size_t)m * N + n;
                if (f32out) ((float*)C)[idx] = v;
                else        ((bf16*)C)[idx]  = __float2bfloat16(v);
            }
        }
    }
}

// ------------------------------ Attention ----------------------------------
// grid (S/64, B*H); 4 waves; wave = 16 q-rows, loops all t in 64-tiles.
// St = K·Q^T (16x16x32 bf16): C layout (col=s=lane&15, row=t=quad*4+reg)
// == A layout of 16x16x16 f16 MFMA -> P feeds PV with no shuffles.
// Denominator over ALL t; triu(k=1) mask on numerator only.
__global__ __launch_bounds__(256)
void attn_kernel(const bf16* __restrict__ Q, const bf16* __restrict__ Kg,
                 const bf16* __restrict__ Vg, bf16* __restrict__ O)
{
    __shared__ alignas(16) short    Ks[64][72];
    __shared__ alignas(16) _Float16 Vs[64][72];   // [d][t] transposed

    const int tid  = threadIdx.x;
    const int lane = tid & 63;
    const int wave = tid >> 6;
    const int q    = lane >> 4;
    const int l15  = lane & 15;
    const int bh   = blockIdx.y;
    const int b    = bh >> 4, h = bh & 15;
    const int s_base = blockIdx.x * 64 + wave * 16;
    const int s_glob = s_base + l15;

    // Q as B-operand of K·Q^T: lane holds Q[s=lane&15][d=quad*8+j]
    const short* qrow = (const short*)Q + (((size_t)(b * 2048 + s_glob) * 16) + h) * 64;
    s16x8 qf0 = *(const s16x8*)(qrow + q * 8);
    s16x8 qf1 = *(const s16x8*)(qrow + 32 + q * 8);

    float m = -1e30f, l = 0.f;
    f32x4 o_acc[4] = {};

    const int trow = tid >> 2;          // 0..63
    const int tcol = (tid & 3) * 16;    // 0,16,32,48

    for (int t0 = 0; t0 < 2048; t0 += 64) {
        const short* krow = (const short*)Kg + (((size_t)(b * 2048 + t0 + trow) * 16) + h) * 64;
        const short* vrow = (const short*)Vg + (((size_t)(b * 2048 + t0 + trow) * 16) + h) * 64;
        s16x8 k0 = *(const s16x8*)(krow + tcol);
        s16x8 k1 = *(const s16x8*)(krow + tcol + 8);
        s16x8 v0 = *(const s16x8*)(vrow + tcol);
        s16x8 v1 = *(const s16x8*)(vrow + tcol + 8);
        __syncthreads();
        *(s16x8*)&Ks[trow][tcol]     = k0;
        *(s16x8*)&Ks[trow][tcol + 8] = k1;
#pragma unroll
        for (int e = 0; e < 8; e++) {
            Vs[tcol + e][trow]     = (_Float16)bfbits2f(v0[e]);
            Vs[tcol + 8 + e][trow] = (_Float16)bfbits2f(v1[e]);
        }
        __syncthreads();

#pragma unroll
        for (int sub = 0; sub < 4; sub++) {
            const int tb = sub * 16;
            s16x8 kf0 = *(const s16x8*)&Ks[tb + l15][q * 8];
            s16x8 kf1 = *(const s16x8*)&Ks[tb + l15][32 + q * 8];
            f32x4 st = {};
            st = __builtin_amdgcn_mfma_f32_16x16x32_bf16(kf0, qf0, st, 0, 0, 0);
            st = __builtin_amdgcn_mfma_f32_16x16x32_bf16(kf1, qf1, st, 0, 0, 0);
            // lane holds scores[t = t0+tb+q*4+r][s = s_glob]
            float sc[4];
#pragma unroll
            for (int r = 0; r < 4; r++) sc[r] = st[r] * 0.125f;
            float mt = fmaxf(fmaxf(sc[0], sc[1]), fmaxf(sc[2], sc[3]));
            mt = fmaxf(mt, __shfl_xor(mt, 16, 64));
            mt = fmaxf(mt, __shfl_xor(mt, 32, 64));
            float m_new = fmaxf(m, mt);
            float alpha = __expf(m - m_new);
            float p[4], rs = 0.f;
#pragma unroll
            for (int r = 0; r < 4; r++) { p[r] = __expf(sc[r] - m_new); rs += p[r]; }
            rs += __shfl_xor(rs, 16, 64);
            rs += __shfl_xor(rs, 32, 64);
            l = l * alpha + rs;      // denominator over ALL t (post-softmax mask)
            m = m_new;
            // masked P -> f16 A-frag (A[m=lane&15=s][k=quad*4+j=t])
            h16x4 pf;
#pragma unroll
            for (int r = 0; r < 4; r++) {
                int tg = t0 + tb + q * 4 + r;
                pf[r] = (_Float16)((tg > s_glob) ? p[r] : 0.f);
            }
            float aO[4];
#pragma unroll
            for (int r = 0; r < 4; r++) aO[r] = __shfl(alpha, q * 4 + r, 64);
#pragma unroll
            for (int dt = 0; dt < 4; dt++) {
                h16x4 vf = *(const h16x4*)&Vs[dt * 16 + l15][tb + q * 4];
                f32x4 c = o_acc[dt];
#pragma unroll
                for (int r = 0; r < 4; r++) c[r] *= aO[r];
                o_acc[dt] = __builtin_amdgcn_mfma_f32_16x16x16f16(pf, vf, c, 0, 0, 0);
            }
        }
    }

    float linv[4];
#pragma unroll
    for (int r = 0; r < 4; r++) linv[r] = 1.f / __shfl(l, q * 4 + r, 64);
#pragma unroll
    for (int dt = 0; dt < 4; dt++)
#pragma unroll
        for (int r = 0; r < 4; r++) {
            int s = s_base + q * 4 + r;
            int d = dt * 16 + l15;
            O[(((size_t)(b * 2048 + s) * 16) + h) * 64 + d] =
                __float2bfloat16(o_acc[dt][r] * linv[r]);
        }
}

// ------------------------------- launcher ----------------------------------
extern "C" void kernel_launch(void* const* d_in, const int* in_sizes, int n_in,
                              void* d_out, int out_size, void* d_ws, size_t ws_size,
                              hipStream_t stream)
{
    const void* x     = d_in[0];
    const void* y     = d_in[1];
    const void* Wq    = d_in[2];
    const void* Wk    = d_in[3];
    const void* Wv    = d_in[4];
    const void* li1_w = d_in[5];
    const void* li1_b = d_in[6];
    const void* ln1_w = d_in[7];
    const void* ln1_b = d_in[8];
    const void* ln2_w = d_in[9];
    const void* ln2_b = d_in[10];
    const void* ln3_w = d_in[11];
    const void* ln3_b = d_in[12];
    const void* li2_w = d_in[13];
    const void* li2_b = d_in[14];
    const void* li3_w = d_in[15];
    const void* li3_b = d_in[16];

    char* w = (char*)d_ws;
    const size_t MB = 1u << 20;
    bf16* xn    = (bf16*)(w + 0 * MB);
    bf16* yn    = (bf16*)(w + 8 * MB);
    bf16* WqT   = (bf16*)(w + 16 * MB);
    bf16* WkT   = (bf16*)(w + 18 * MB);
    bf16* WvT   = (bf16*)(w + 20 * MB);
    bf16* li1T  = (bf16*)(w + 22 * MB);
    bf16* li2T  = (bf16*)(w + 24 * MB);
    bf16* li3T  = (bf16*)(w + 32 * MB);
    bf16* xout  = (bf16*)(w + 40 * MB);
    bf16* Qb    = (bf16*)(w + 48 * MB);
    bf16* Kb    = (bf16*)(w + 56 * MB);
    bf16* Vb    = (bf16*)(w + 64 * MB);
    bf16* h2    = (bf16*)(w + 48 * MB);  // reuses Q,K,V after attention
    bf16* xc    = (bf16*)(w + 80 * MB);  // canonical bf16 copy of x (residual)
    int*  flag  = (int*) (w + 88 * MB);
    bf16* li1bc = (bf16*)(w + 88 * MB + 4096);
    bf16* li2bc = (bf16*)(w + 88 * MB + 8192);
    bf16* li3bc = (bf16*)(w + 88 * MB + 24576);
    bf16* Ob    = yn;                    // reuse yn after K,V projections
    bf16* hn    = xn;                    // reuse xn after Q projection

    // 0. dtype detection (deterministic per input -> graph-safe)
    detect_dtype<<<1, 256, 0, stream>>>((const short*)x, flag);

    // 1. canonical conversions
    conv_to_bf16<<<16384, 256, 0, stream>>>(x, xc, 4194304, flag);
    conv_to_bf16<<<4, 256, 0, stream>>>(li1_b, li1bc, 1024, flag);
    conv_to_bf16<<<16, 256, 0, stream>>>(li2_b, li2bc, 4096, flag);
    conv_to_bf16<<<4, 256, 0, stream>>>(li3_b, li3bc, 1024, flag);

    // 2. LayerNorms (flag-aware raw reads)
    ln_kernel<<<4096, 256, 0, stream>>>(x, ln1_w, ln1_b, xn, flag, 0);
    ln_kernel<<<4096, 256, 0, stream>>>(y, ln2_w, ln2_b, yn, flag, 0);

    // 3. weight re-layouts
    pack_qkv_w<<<4096, 256, 0, stream>>>(Wq, WqT, flag);
    pack_qkv_w<<<4096, 256, 0, stream>>>(Wk, WkT, flag);
    pack_qkv_w<<<4096, 256, 0, stream>>>(Wv, WvT, flag);
    transpose2d<<<4096, 256, 0, stream>>>(li1_w, li1T, 1024, 1024, flag);
    transpose2d<<<16384, 256, 0, stream>>>(li2_w, li2T, 1024, 4096, flag);
    transpose2d<<<16384, 256, 0, stream>>>(li3_w, li3T, 4096, 1024, flag);

    // 4. QKV projections -> [B,S,H,D]
    gemm_bt<<<dim3(32, 8), 256, 0, stream>>>(xn, WqT, nullptr, nullptr, Qb, 4096, 1024, 1024, 0, flag, 0);
    gemm_bt<<<dim3(32, 8), 256, 0, stream>>>(yn, WkT, nullptr, nullptr, Kb, 4096, 1024, 1024, 0, flag, 0);
    gemm_bt<<<dim3(32, 8), 256, 0, stream>>>(yn, WvT, nullptr, nullptr, Vb, 4096, 1024, 1024, 0, flag, 0);

    // 5. attention -> O [B,S,H*D]
    attn_kernel<<<dim3(32, 32), 256, 0, stream>>>(Qb, Kb, Vb, Ob);

    // 6. x_out = x + O @ li1_w + li1_b
    gemm_bt<<<dim3(32, 8), 256, 0, stream>>>(Ob, li1T, li1bc, xc, xout, 4096, 1024, 1024, 0, flag, 0);

    // 7. hn = LN3(x_out)  (x operand is internal bf16 -> x_is_bf16=1)
    ln_kernel<<<4096, 256, 0, stream>>>(xout, ln3_w, ln3_b, hn, flag, 1);

    // 8. h2 = gelu(hn @ li2_w + li2_b)
    gemm_bt<<<dim3(32, 32), 256, 0, stream>>>(hn, li2T, li2bc, nullptr, h2, 4096, 4096, 1024, 1, flag, 0);

    // 9. out = x_out + h2 @ li3_w + li3_b   (dtype-matched store)
    gemm_bt<<<dim3(32, 8), 256, 0, stream>>>(h2, li3T, li3bc, xout, d_out, 4096, 1024, 4096, 0, flag, 1);
}

// Round 5
// 591.012 us; speedup vs baseline: 1.1898x; 1.1898x over previous
//
#include <hip/hip_runtime.h>
#include <hip/hip_bf16.h>

// ---------------------------------------------------------------------------
// MultiHeadAttention block on MI355X (gfx950). Inputs are float32 (verified
// round 3 via device-side dtype detection, kept for robustness). Internal
// pipeline bf16 MFMA, fp32 accumulate.
//   xn=LN(x), yn=LN(y); Q=xn@Wq, K=yn@Wk, V=yn@Wv (weights packed [H*D,C])
//   A=softmax(QK^T/8) over all t; triu(k=1) mask applied AFTER softmax
//     -> denominator l is a PURE SUM over all t (no online-max needed;
//        scores bounded ~N(0,0.34^2), exp clamped for safety)
//   O=A@V; x_out = x + O@li1_w + li1_b
//   out = x_out + gelu_exact(LN3(x_out)@li2_w+li2_b)@li3_w + li3_b
// Round-4 NaN root cause: Vs swizzle column was not a permutation
// (vcol = swz*16 + (trow&3) loses trow bits -> uninit LDS into PV MFMA).
// Fixed: vcol = ((trow>>4) ^ tchunk)*16 + (trow&15), matching the read's
// col' = ((t>>4) ^ (d>>4))*16 + (t&15).
// Workspace (88MB + 32KB):
//   [0,8M) xn/hn  [8,16M) yn/O  [16,24M) WqT,WkT,WvT,li1T  [24,32M) li2T
//   [32,40M) li3T  [40,48M) xout  [48,80M) Q,K,V -> h2  [80,88M) xc
//   [88M+0) dtype flag, [88M+4K..) canonical biases
// ---------------------------------------------------------------------------

typedef __hip_bfloat16 bf16;
typedef __attribute__((ext_vector_type(8))) short  s16x8;
typedef __attribute__((ext_vector_type(4))) short  s16x4;
typedef __attribute__((ext_vector_type(4))) float  f32x4;
typedef __attribute__((ext_vector_type(4))) _Float16 h16x4;

__device__ __forceinline__ float bfbits2f(short s) {
    return __uint_as_float(((unsigned)(unsigned short)s) << 16);
}
__device__ __forceinline__ float load_in(const void* p, size_t i, int f32) {
    return f32 ? ((const float*)p)[i] : bfbits2f(((const short*)p)[i]);
}

// ------------------------- dtype detection ---------------------------------
__global__ __launch_bounds__(256)
void detect_dtype(const short* __restrict__ x, int* __restrict__ flag)
{
    const int tid = threadIdx.x;
    int cnt = 0;
#pragma unroll
    for (int e = 0; e < 16; e++) {
        int idx = (tid * 16 + e) * 2;            // even shorts only
        int ex  = (x[idx] >> 7) & 0xFF;
        if (ex >= 113 && ex <= 142) cnt++;
    }
#pragma unroll
    for (int off = 1; off < 64; off <<= 1) cnt += __shfl_xor(cnt, off, 64);
    __shared__ int sh[4];
    if ((tid & 63) == 0) sh[tid >> 6] = cnt;
    __syncthreads();
    if (tid == 0) {
        int tot = sh[0] + sh[1] + sh[2] + sh[3];  // bf16: ~4096, f32: ~480
        flag[0] = (tot < 2458) ? 1 : 0;           // 1 == inputs are float32
    }
}

// --------------------- conversion / tiled transposes -----------------------
__global__ __launch_bounds__(256)
void conv_to_bf16(const void* __restrict__ in, bf16* __restrict__ out, int n,
                  const int* __restrict__ flag)
{
    int i = (blockIdx.x * 256 + threadIdx.x) * 4;
    if (i >= n) return;
    if (flag[0]) {
        f32x4 v = *(const f32x4*)((const float*)in + i);
#pragma unroll
        for (int e = 0; e < 4; e++) out[i + e] = __float2bfloat16(v[e]);
    } else {
        *(s16x4*)((short*)out + i) = *(const s16x4*)((const short*)in + i);
    }
}

// in [R,Cc] -> out [Cc,R], 32x32 LDS tiles, coalesced both sides
__global__ __launch_bounds__(256)
void transpose_tiled(const void* __restrict__ in, bf16* __restrict__ out,
                     int R, int Cc, const int* __restrict__ flag)
{
    __shared__ float tile[32][33];
    const int f32 = flag[0];
    const int tx = threadIdx.x & 31, ty = threadIdx.x >> 5;   // ty 0..7
    const int c0 = blockIdx.x * 32, r0 = blockIdx.y * 32;
#pragma unroll
    for (int i = 0; i < 4; i++)
        tile[ty + i * 8][tx] = load_in(in, (size_t)(r0 + ty + i * 8) * Cc + c0 + tx, f32);
    __syncthreads();
#pragma unroll
    for (int i = 0; i < 4; i++)
        out[(size_t)(c0 + ty + i * 8) * R + r0 + tx] = __float2bfloat16(tile[tx][ty + i * 8]);
}

// Wq [H][C=1024][D=64] -> WqT [H][D][C]  (per-head 1024x64 transpose)
__global__ __launch_bounds__(256)
void pack_qkv_tiled(const void* __restrict__ in, bf16* __restrict__ out,
                    const int* __restrict__ flag)
{
    __shared__ float tile[32][33];
    const int f32 = flag[0];
    const int tx = threadIdx.x & 31, ty = threadIdx.x >> 5;
    const int c0 = blockIdx.x * 32, r0 = blockIdx.y * 32;   // c: D, r: C
    const size_t base = (size_t)blockIdx.z * 1024 * 64;
#pragma unroll
    for (int i = 0; i < 4; i++)
        tile[ty + i * 8][tx] = load_in(in, base + (size_t)(r0 + ty + i * 8) * 64 + c0 + tx, f32);
    __syncthreads();
#pragma unroll
    for (int i = 0; i < 4; i++)
        out[base + (size_t)(c0 + ty + i * 8) * 1024 + r0 + tx] =
            __float2bfloat16(tile[tx][ty + i * 8]);
}

// ------------------------------- LayerNorm ---------------------------------
__global__ __launch_bounds__(256)
void ln_kernel(const void* __restrict__ x, const void* __restrict__ w,
               const void* __restrict__ bv, bf16* __restrict__ out,
               const int* __restrict__ flag, int x_is_bf16)
{
    const int f32  = flag[0];
    const int xf32 = x_is_bf16 ? 0 : f32;
    const int row  = blockIdx.x;
    const int tid  = threadIdx.x;
    const int lane = tid & 63;
    const int wave = tid >> 6;
    const size_t base = (size_t)row * 1024 + tid * 4;

    float v[4];
    float sum = 0.f, ss = 0.f;
#pragma unroll
    for (int e = 0; e < 4; e++) {
        v[e] = load_in(x, base + e, xf32);
        sum += v[e]; ss += v[e] * v[e];
    }
#pragma unroll
    for (int off = 1; off < 64; off <<= 1) {
        sum += __shfl_xor(sum, off, 64);
        ss  += __shfl_xor(ss,  off, 64);
    }
    __shared__ float sh1[4], sh2[4];
    if (lane == 0) { sh1[wave] = sum; sh2[wave] = ss; }
    __syncthreads();
    float t1 = sh1[0] + sh1[1] + sh1[2] + sh1[3];
    float t2 = sh2[0] + sh2[1] + sh2[2] + sh2[3];
    float mu   = t1 * (1.f / 1024.f);
    float var  = t2 * (1.f / 1024.f) - mu * mu;
    float rstd = rsqrtf(var + 1e-5f);

#pragma unroll
    for (int e = 0; e < 4; e++) {
        float ov = (v[e] - mu) * rstd * load_in(w, tid * 4 + e, f32)
                 + load_in(bv, tid * 4 + e, f32);
        out[base + e] = __float2bfloat16(ov);
    }
}

// ------------------------------ GEMM (B^T) ---------------------------------
__global__ __launch_bounds__(256)
void gemm_bt(const bf16* __restrict__ A, const bf16* __restrict__ Bt,
             const bf16* __restrict__ bias, const bf16* __restrict__ res,
             void* __restrict__ C, int M, int N, int K, int act,
             const int* __restrict__ dflag, int final_out)
{
    __shared__ alignas(16) short As[128][40];   // pad 40: 80B rows, 2-way only
    __shared__ alignas(16) short Bs[128][40];

    const int f32out = final_out ? dflag[0] : 0;
    const int tid  = threadIdx.x;
    const int lane = tid & 63;
    const int wave = tid >> 6;
    const int q    = lane >> 4;
    const int l15  = lane & 15;
    const int wm   = (wave >> 1) * 64;
    const int wn   = (wave & 1) * 64;
    const int bm   = blockIdx.x * 128;
    const int bn   = blockIdx.y * 128;

    const int lrow = tid >> 2;        // 0..63
    const int lcol = (tid & 3) * 8;   // 0,8,16,24

    f32x4 acc[4][4] = {};

    for (int k0 = 0; k0 < K; k0 += 32) {
        const short* Ap = (const short*)A  + (size_t)(bm + lrow) * K + k0 + lcol;
        const short* Bp = (const short*)Bt + (size_t)(bn + lrow) * K + k0 + lcol;
        s16x8 a0 = *(const s16x8*)Ap;
        s16x8 a1 = *(const s16x8*)(Ap + (size_t)64 * K);
        s16x8 b0 = *(const s16x8*)Bp;
        s16x8 b1 = *(const s16x8*)(Bp + (size_t)64 * K);
        __syncthreads();
        *(s16x8*)&As[lrow][lcol]      = a0;
        *(s16x8*)&As[lrow + 64][lcol] = a1;
        *(s16x8*)&Bs[lrow][lcol]      = b0;
        *(s16x8*)&Bs[lrow + 64][lcol] = b1;
        __syncthreads();

        s16x8 af[4], bfrag[4];
#pragma unroll
        for (int i = 0; i < 4; i++) af[i]    = *(const s16x8*)&As[wm + i * 16 + l15][q * 8];
#pragma unroll
        for (int j = 0; j < 4; j++) bfrag[j] = *(const s16x8*)&Bs[wn + j * 16 + l15][q * 8];
#pragma unroll
        for (int i = 0; i < 4; i++)
#pragma unroll
            for (int j = 0; j < 4; j++)
                acc[i][j] = __builtin_amdgcn_mfma_f32_16x16x32_bf16(af[i], bfrag[j], acc[i][j], 0, 0, 0);
    }

    // epilogue: C/D layout col=lane&15, row=quad*4+reg
#pragma unroll
    for (int i = 0; i < 4; i++) {
#pragma unroll
        for (int j = 0; j < 4; j++) {
            int n = bn + wn + j * 16 + l15;
            float bvv = bias ? __bfloat162float(bias[n]) : 0.f;
#pragma unroll
            for (int r = 0; r < 4; r++) {
                int m = bm + wm + i * 16 + q * 4 + r;
                float v = acc[i][j][r] + bvv;
                if (act) v = 0.5f * v * (1.f + erff(v * 0.70710678118f));
                if (res) v += __bfloat162float(res[(size_t)m * N + n]);
                size_t idx = (size_t)m * N + n;
                if (f32out) ((float*)C)[idx] = v;
                else        ((bf16*)C)[idx]  = __float2bfloat16(v);
            }
        }
    }
}

// ------------------------------ Attention ----------------------------------
// grid (S/64, B*H); 4 waves; wave = 16 q-rows, loops all t in 64-tiles.
// St = K·Q^T (16x16x32 bf16): C layout (col=s=lane&15, row=t=quad*4+reg)
// == A layout of 16x16x16 f16 MFMA -> P feeds PV with no shuffles.
// Post-softmax mask => l is a pure sum (no online max/rescale):
//   - l accumulated lane-locally, reduced ONCE at the end (2 shfls total)
//   - PV + pf skipped for fully-masked subs (rel<0, ~half) [wave-uniform]
//   - V staging skipped for tiles t0 < sblk [block-uniform]
// LDS swizzles (16-elem chunks):
//   Ks[t][d']  : d-chunk' = d-chunk ^ ((t>>2)&3)   (write key == read key)
//   Vs[d][t']  : t-chunk' = (t>>4) ^ (d>>4)         (write matches PV read)
__global__ __launch_bounds__(256)
void attn_kernel(const bf16* __restrict__ Q, const bf16* __restrict__ Kg,
                 const bf16* __restrict__ Vg, bf16* __restrict__ O)
{
    __shared__ alignas(16) short    Ks[64][72];   // [t][d'], swizzled cols
    __shared__ alignas(16) _Float16 Vs[64][72];   // [d][t'], swizzled cols

    const int tid  = threadIdx.x;
    const int lane = tid & 63;
    const int wave = tid >> 6;
    const int q    = lane >> 4;
    const int l15  = lane & 15;
    const int bh   = blockIdx.y;
    const int b    = bh >> 4, h = bh & 15;
    const int sblk   = blockIdx.x * 64;
    const int s_base = sblk + wave * 16;
    const int s_glob = s_base + l15;

    // Q as B-operand of K·Q^T: lane holds Q[s=lane&15][d=quad*8+j]
    const short* qrow = (const short*)Q + (((size_t)(b * 2048 + s_glob) * 16) + h) * 64;
    s16x8 qf0 = *(const s16x8*)(qrow + q * 8);
    s16x8 qf1 = *(const s16x8*)(qrow + 32 + q * 8);

    float l_lane = 0.f;
    f32x4 o_acc[4] = {};

    const int trow   = tid >> 2;                        // t within tile, 0..63
    const int tchunk = tid & 3;                         // 16-elem d-chunk
    const int kswz   = (tchunk ^ (trow >> 2)) & 3;      // Ks write chunk
    const int vcol   = (((trow >> 4) ^ tchunk) & 3) * 16 + (trow & 15); // Vs col
    const int ksw    = l15 >> 2;                        // Ks read swizzle key

    for (int t0 = 0; t0 < 2048; t0 += 64) {
        const bool needV = (t0 >= sblk);
        const short* krow = (const short*)Kg + (((size_t)(b * 2048 + t0 + trow) * 16) + h) * 64;
        s16x8 k0 = *(const s16x8*)(krow + tchunk * 16);
        s16x8 k1 = *(const s16x8*)(krow + tchunk * 16 + 8);
        s16x8 v0, v1;
        if (needV) {
            const short* vrow = (const short*)Vg + (((size_t)(b * 2048 + t0 + trow) * 16) + h) * 64;
            v0 = *(const s16x8*)(vrow + tchunk * 16);
            v1 = *(const s16x8*)(vrow + tchunk * 16 + 8);
        }
        __syncthreads();
        *(s16x8*)&Ks[trow][kswz * 16]     = k0;
        *(s16x8*)&Ks[trow][kswz * 16 + 8] = k1;
        if (needV) {
            // Vs[d][vcol]; d = tchunk*16 + e, col key (trow>>4)^tchunk
#pragma unroll
            for (int e = 0; e < 8; e++) {
                Vs[tchunk * 16 + e][vcol]     = (_Float16)bfbits2f(v0[e]);
                Vs[tchunk * 16 + 8 + e][vcol] = (_Float16)bfbits2f(v1[e]);
            }
        }
        __syncthreads();

#pragma unroll
        for (int sub = 0; sub < 4; sub++) {
            const int tb  = sub * 16;
            const int rel = t0 + tb - s_base;   // wave-uniform
            s16x8 kf0 = *(const s16x8*)&Ks[tb + l15][(((q >> 1) ^ ksw) & 3) * 16 + (q & 1) * 8];
            s16x8 kf1 = *(const s16x8*)&Ks[tb + l15][((((q >> 1) + 2) ^ ksw) & 3) * 16 + (q & 1) * 8];
            f32x4 st = {};
            st = __builtin_amdgcn_mfma_f32_16x16x32_bf16(kf0, qf0, st, 0, 0, 0);
            st = __builtin_amdgcn_mfma_f32_16x16x32_bf16(kf1, qf1, st, 0, 0, 0);
            // lane holds scores[t = t0+tb+q*4+r][s = s_glob]
            float p[4];
#pragma unroll
            for (int r = 0; r < 4; r++) {
                float sc = st[r] * 0.125f;
                p[r] = __expf(fminf(sc, 60.f));   // no max-sub: scores bounded
                l_lane += p[r];
            }
            if (rel >= 0) {                        // any unmasked numerator?
                h16x4 pf;
                if (rel == 0) {                    // boundary sub: t=s_base+q*4+r
#pragma unroll
                    for (int r = 0; r < 4; r++)
                        pf[r] = (q * 4 + r > l15) ? (_Float16)p[r] : (_Float16)0.f;
                } else {
#pragma unroll
                    for (int r = 0; r < 4; r++) pf[r] = (_Float16)p[r];
                }
#pragma unroll
                for (int dt = 0; dt < 4; dt++) {
                    h16x4 vf = *(const h16x4*)&Vs[dt * 16 + l15]
                                                 [(((tb >> 4) ^ dt) & 3) * 16 + q * 4];
                    o_acc[dt] = __builtin_amdgcn_mfma_f32_16x16x16f16(pf, vf, o_acc[dt], 0, 0, 0);
                }
            }
        }
    }

    // single final l-reduction: sum over quads (s = l15 columns)
    float l = l_lane;
    l += __shfl_xor(l, 16, 64);
    l += __shfl_xor(l, 32, 64);
    float linv[4];
#pragma unroll
    for (int r = 0; r < 4; r++) linv[r] = 1.f / __shfl(l, q * 4 + r, 64);
#pragma unroll
    for (int dt = 0; dt < 4; dt++)
#pragma unroll
        for (int r = 0; r < 4; r++) {
            int s = s_base + q * 4 + r;
            int d = dt * 16 + l15;
            O[(((size_t)(b * 2048 + s) * 16) + h) * 64 + d] =
                __float2bfloat16(o_acc[dt][r] * linv[r]);
        }
}

// ------------------------------- launcher ----------------------------------
extern "C" void kernel_launch(void* const* d_in, const int* in_sizes, int n_in,
                              void* d_out, int out_size, void* d_ws, size_t ws_size,
                              hipStream_t stream)
{
    const void* x     = d_in[0];
    const void* y     = d_in[1];
    const void* Wq    = d_in[2];
    const void* Wk    = d_in[3];
    const void* Wv    = d_in[4];
    const void* li1_w = d_in[5];
    const void* li1_b = d_in[6];
    const void* ln1_w = d_in[7];
    const void* ln1_b = d_in[8];
    const void* ln2_w = d_in[9];
    const void* ln2_b = d_in[10];
    const void* ln3_w = d_in[11];
    const void* ln3_b = d_in[12];
    const void* li2_w = d_in[13];
    const void* li2_b = d_in[14];
    const void* li3_w = d_in[15];
    const void* li3_b = d_in[16];

    char* w = (char*)d_ws;
    const size_t MB = 1u << 20;
    bf16* xn    = (bf16*)(w + 0 * MB);
    bf16* yn    = (bf16*)(w + 8 * MB);
    bf16* WqT   = (bf16*)(w + 16 * MB);
    bf16* WkT   = (bf16*)(w + 18 * MB);
    bf16* WvT   = (bf16*)(w + 20 * MB);
    bf16* li1T  = (bf16*)(w + 22 * MB);
    bf16* li2T  = (bf16*)(w + 24 * MB);
    bf16* li3T  = (bf16*)(w + 32 * MB);
    bf16* xout  = (bf16*)(w + 40 * MB);
    bf16* Qb    = (bf16*)(w + 48 * MB);
    bf16* Kb    = (bf16*)(w + 56 * MB);
    bf16* Vb    = (bf16*)(w + 64 * MB);
    bf16* h2    = (bf16*)(w + 48 * MB);  // reuses Q,K,V after attention
    bf16* xc    = (bf16*)(w + 80 * MB);  // canonical bf16 copy of x (residual)
    int*  flag  = (int*) (w + 88 * MB);
    bf16* li1bc = (bf16*)(w + 88 * MB + 4096);
    bf16* li2bc = (bf16*)(w + 88 * MB + 8192);
    bf16* li3bc = (bf16*)(w + 88 * MB + 24576);
    bf16* Ob    = yn;                    // reuse yn after K,V projections
    bf16* hn    = xn;                    // reuse xn after Q projection

    // 0. dtype detection (deterministic per input -> graph-safe)
    detect_dtype<<<1, 256, 0, stream>>>((const short*)x, flag);

    // 1. canonical conversions
    conv_to_bf16<<<4096, 256, 0, stream>>>(x, xc, 4194304, flag);
    conv_to_bf16<<<1, 256, 0, stream>>>(li1_b, li1bc, 1024, flag);
    conv_to_bf16<<<4, 256, 0, stream>>>(li2_b, li2bc, 4096, flag);
    conv_to_bf16<<<1, 256, 0, stream>>>(li3_b, li3bc, 1024, flag);

    // 2. LayerNorms (flag-aware raw reads)
    ln_kernel<<<4096, 256, 0, stream>>>(x, ln1_w, ln1_b, xn, flag, 0);
    ln_kernel<<<4096, 256, 0, stream>>>(y, ln2_w, ln2_b, yn, flag, 0);

    // 3. weight re-layouts (LDS-tiled, coalesced)
    pack_qkv_tiled<<<dim3(2, 32, 16), 256, 0, stream>>>(Wq, WqT, flag);
    pack_qkv_tiled<<<dim3(2, 32, 16), 256, 0, stream>>>(Wk, WkT, flag);
    pack_qkv_tiled<<<dim3(2, 32, 16), 256, 0, stream>>>(Wv, WvT, flag);
    transpose_tiled<<<dim3(32, 32),  256, 0, stream>>>(li1_w, li1T, 1024, 1024, flag);
    transpose_tiled<<<dim3(128, 32), 256, 0, stream>>>(li2_w, li2T, 1024, 4096, flag);
    transpose_tiled<<<dim3(32, 128), 256, 0, stream>>>(li3_w, li3T, 4096, 1024, flag);

    // 4. QKV projections -> [B,S,H,D]
    gemm_bt<<<dim3(32, 8), 256, 0, stream>>>(xn, WqT, nullptr, nullptr, Qb, 4096, 1024, 1024, 0, flag, 0);
    gemm_bt<<<dim3(32, 8), 256, 0, stream>>>(yn, WkT, nullptr, nullptr, Kb, 4096, 1024, 1024, 0, flag, 0);
    gemm_bt<<<dim3(32, 8), 256, 0, stream>>>(yn, WvT, nullptr, nullptr, Vb, 4096, 1024, 1024, 0, flag, 0);

    // 5. attention -> O [B,S,H*D]
    attn_kernel<<<dim3(32, 32), 256, 0, stream>>>(Qb, Kb, Vb, Ob);

    // 6. x_out = x + O @ li1_w + li1_b
    gemm_bt<<<dim3(32, 8), 256, 0, stream>>>(Ob, li1T, li1bc, xc, xout, 4096, 1024, 1024, 0, flag, 0);

    // 7. hn = LN3(x_out)  (x operand is internal bf16)
    ln_kernel<<<4096, 256, 0, stream>>>(xout, ln3_w, ln3_b, hn, flag, 1);

    // 8. h2 = gelu(hn @ li2_w + li2_b)
    gemm_bt<<<dim3(32, 32), 256, 0, stream>>>(hn, li2T, li2bc, nullptr, h2, 4096, 4096, 1024, 1, flag, 0);

    // 9. out = x_out + h2 @ li3_w + li3_b   (dtype-matched store)
    gemm_bt<<<dim3(32, 8), 256, 0, stream>>>(h2, li3T, li3bc, xout, d_out, 4096, 1024, 4096, 0, flag, 1);
}

// Round 6
// 543.054 us; speedup vs baseline: 1.2949x; 1.0883x over previous
//
#include <hip/hip_runtime.h>
#include <hip/hip_bf16.h>

// ---------------------------------------------------------------------------
// MultiHeadAttention block on MI355X (gfx950). Inputs float32 (device-detected,
// kept for robustness). Internal pipeline bf16 MFMA, fp32 accumulate.
// Round-6 changes (GEMM only):
//   * m97-style staging: global_load_lds width=16 into UNPADDED [128][32] LDS
//     tiles (wave-uniform base + lane*16B), ds_read_b128 fragments.
//   * BN templated: 128x64 tiles for N=1024 GEMMs (512 blocks = 2/CU instead
//     of 256 = 1/CU -> fixes OccupancyPercent=11% on li3), 128x128 for li2.
//   * K+V projection fused into one N=2048 GEMM (WkT/WvT contiguous);
//     attention reads fused KV [4096][2048] (k at col h*64, v at +1024).
// Workspace (88MB + 32KB):
//   [0,8M) xn/hn  [8,16M) yn/O  [16,24M) WqT,WkT,WvT,li1T  [24,32M) li2T
//   [32,40M) li3T  [40,48M) xout  [48,56M) Qb  [56,72M) KVb
//   [48,80M) h2 (after attn)  [80,88M) xc  [88M) flag + biases
// ---------------------------------------------------------------------------

typedef __hip_bfloat16 bf16;
typedef __attribute__((ext_vector_type(8))) short  s16x8;
typedef __attribute__((ext_vector_type(4))) short  s16x4;
typedef __attribute__((ext_vector_type(4))) float  f32x4;
typedef __attribute__((ext_vector_type(4))) _Float16 h16x4;

__device__ __forceinline__ float bfbits2f(short s) {
    return __uint_as_float(((unsigned)(unsigned short)s) << 16);
}
__device__ __forceinline__ float load_in(const void* p, size_t i, int f32) {
    return f32 ? ((const float*)p)[i] : bfbits2f(((const short*)p)[i]);
}
// async global->LDS, 16B/lane; lds base MUST be wave-uniform (HW scatters
// lane i to base + i*16) [m104/m108]
__device__ __forceinline__ void async16(const short* g, short* l) {
    __builtin_amdgcn_global_load_lds(
        (const __attribute__((address_space(1))) void*)g,
        (__attribute__((address_space(3))) void*)l, 16, 0, 0);
}

// ------------------------- dtype detection ---------------------------------
__global__ __launch_bounds__(256)
void detect_dtype(const short* __restrict__ x, int* __restrict__ flag)
{
    const int tid = threadIdx.x;
    int cnt = 0;
#pragma unroll
    for (int e = 0; e < 16; e++) {
        int idx = (tid * 16 + e) * 2;            // even shorts only
        int ex  = (x[idx] >> 7) & 0xFF;
        if (ex >= 113 && ex <= 142) cnt++;
    }
#pragma unroll
    for (int off = 1; off < 64; off <<= 1) cnt += __shfl_xor(cnt, off, 64);
    __shared__ int sh[4];
    if ((tid & 63) == 0) sh[tid >> 6] = cnt;
    __syncthreads();
    if (tid == 0) {
        int tot = sh[0] + sh[1] + sh[2] + sh[3];  // bf16: ~4096, f32: ~480
        flag[0] = (tot < 2458) ? 1 : 0;           // 1 == inputs are float32
    }
}

// --------------------- conversion / tiled transposes -----------------------
__global__ __launch_bounds__(256)
void conv_to_bf16(const void* __restrict__ in, bf16* __restrict__ out, int n,
                  const int* __restrict__ flag)
{
    int i = (blockIdx.x * 256 + threadIdx.x) * 4;
    if (i >= n) return;
    if (flag[0]) {
        f32x4 v = *(const f32x4*)((const float*)in + i);
#pragma unroll
        for (int e = 0; e < 4; e++) out[i + e] = __float2bfloat16(v[e]);
    } else {
        *(s16x4*)((short*)out + i) = *(const s16x4*)((const short*)in + i);
    }
}

// in [R,Cc] -> out [Cc,R], 32x32 LDS tiles, coalesced both sides
__global__ __launch_bounds__(256)
void transpose_tiled(const void* __restrict__ in, bf16* __restrict__ out,
                     int R, int Cc, const int* __restrict__ flag)
{
    __shared__ float tile[32][33];
    const int f32 = flag[0];
    const int tx = threadIdx.x & 31, ty = threadIdx.x >> 5;   // ty 0..7
    const int c0 = blockIdx.x * 32, r0 = blockIdx.y * 32;
#pragma unroll
    for (int i = 0; i < 4; i++)
        tile[ty + i * 8][tx] = load_in(in, (size_t)(r0 + ty + i * 8) * Cc + c0 + tx, f32);
    __syncthreads();
#pragma unroll
    for (int i = 0; i < 4; i++)
        out[(size_t)(c0 + ty + i * 8) * R + r0 + tx] = __float2bfloat16(tile[tx][ty + i * 8]);
}

// Wq [H][C=1024][D=64] -> WqT [H][D][C]  (per-head 1024x64 transpose)
__global__ __launch_bounds__(256)
void pack_qkv_tiled(const void* __restrict__ in, bf16* __restrict__ out,
                    const int* __restrict__ flag)
{
    __shared__ float tile[32][33];
    const int f32 = flag[0];
    const int tx = threadIdx.x & 31, ty = threadIdx.x >> 5;
    const int c0 = blockIdx.x * 32, r0 = blockIdx.y * 32;   // c: D, r: C
    const size_t base = (size_t)blockIdx.z * 1024 * 64;
#pragma unroll
    for (int i = 0; i < 4; i++)
        tile[ty + i * 8][tx] = load_in(in, base + (size_t)(r0 + ty + i * 8) * 64 + c0 + tx, f32);
    __syncthreads();
#pragma unroll
    for (int i = 0; i < 4; i++)
        out[base + (size_t)(c0 + ty + i * 8) * 1024 + r0 + tx] =
            __float2bfloat16(tile[tx][ty + i * 8]);
}

// ------------------------------- LayerNorm ---------------------------------
__global__ __launch_bounds__(256)
void ln_kernel(const void* __restrict__ x, const void* __restrict__ w,
               const void* __restrict__ bv, bf16* __restrict__ out,
               const int* __restrict__ flag, int x_is_bf16)
{
    const int f32  = flag[0];
    const int xf32 = x_is_bf16 ? 0 : f32;
    const int row  = blockIdx.x;
    const int tid  = threadIdx.x;
    const int lane = tid & 63;
    const int wave = tid >> 6;
    const size_t base = (size_t)row * 1024 + tid * 4;

    float v[4];
    float sum = 0.f, ss = 0.f;
#pragma unroll
    for (int e = 0; e < 4; e++) {
        v[e] = load_in(x, base + e, xf32);
        sum += v[e]; ss += v[e] * v[e];
    }
#pragma unroll
    for (int off = 1; off < 64; off <<= 1) {
        sum += __shfl_xor(sum, off, 64);
        ss  += __shfl_xor(ss,  off, 64);
    }
    __shared__ float sh1[4], sh2[4];
    if (lane == 0) { sh1[wave] = sum; sh2[wave] = ss; }
    __syncthreads();
    float t1 = sh1[0] + sh1[1] + sh1[2] + sh1[3];
    float t2 = sh2[0] + sh2[1] + sh2[2] + sh2[3];
    float mu   = t1 * (1.f / 1024.f);
    float var  = t2 * (1.f / 1024.f) - mu * mu;
    float rstd = rsqrtf(var + 1e-5f);

#pragma unroll
    for (int e = 0; e < 4; e++) {
        float ov = (v[e] - mu) * rstd * load_in(w, tid * 4 + e, f32)
                 + load_in(bv, tid * 4 + e, f32);
        out[base + e] = __float2bfloat16(ov);
    }
}

// ------------------------------ GEMM (B^T) ---------------------------------
// C[M,N] = A[M,K] @ Bt[N,K]^T, bf16 in, fp32 acc; bias/gelu/residual epilogue.
// 256 thr = 4 waves; tile 128 x BN (BN=128: wave 64x64 / BN=64: wave 64x32).
// Staging: global_load_lds width 16 into unpadded [rows][32]-short LDS
// (wave-uniform base; lane i lands at row i/4, chunk i%4 — global addresses
// computed to match). Fragments: single ds_read_b128 per 16x16x32 operand.
template<int BN>
__global__ __launch_bounds__(256)
void gemm_bt(const bf16* __restrict__ A, const bf16* __restrict__ Bt,
             const bf16* __restrict__ bias, const bf16* __restrict__ res,
             void* __restrict__ C, int M, int N, int K, int act,
             const int* __restrict__ dflag, int final_out)
{
    constexpr int JN = BN / 32;                 // per-wave N MFMA tiles (4 or 2)
    __shared__ alignas(16) short As[128][32];
    __shared__ alignas(16) short Bs[BN][32];

    const int f32out = final_out ? dflag[0] : 0;
    const int tid  = threadIdx.x;
    const int lane = tid & 63;
    const int wave = tid >> 6;
    const int q    = lane >> 4;
    const int l15  = lane & 15;
    const int wm   = (wave >> 1) * 64;
    const int wn   = (wave & 1) * (BN / 2);
    const int bm   = blockIdx.x * 128;
    const int bn   = blockIdx.y * BN;

    const int lr = lane >> 2;        // row within a 16-row group
    const int lc = (lane & 3) * 8;   // col offset (shorts)

    f32x4 acc[4][JN] = {};

    const short* Abase = (const short*)A  + (size_t)(bm + wave * 32 + lr) * K + lc;
    const short* Bbase;
    if (BN == 128) Bbase = (const short*)Bt + (size_t)(bn + wave * 32 + lr) * K + lc;
    else           Bbase = (const short*)Bt + (size_t)(bn + wave * 16 + lr) * K + lc;

    for (int k0 = 0; k0 < K; k0 += 32) {
        __syncthreads();                         // all waves done reading LDS
        async16(Abase + k0,                &As[wave * 32][0]);
        async16(Abase + k0 + (size_t)16 * K, &As[wave * 32 + 16][0]);
        if (BN == 128) {
            async16(Bbase + k0,                &Bs[wave * 32][0]);
            async16(Bbase + k0 + (size_t)16 * K, &Bs[wave * 32 + 16][0]);
        } else {
            async16(Bbase + k0, &Bs[wave * 16][0]);
        }
        __syncthreads();                         // vmcnt(0) drain -> LDS ready

        s16x8 af[4], bfrag[JN];
#pragma unroll
        for (int i = 0; i < 4; i++)  af[i]    = *(const s16x8*)&As[wm + i * 16 + l15][q * 8];
#pragma unroll
        for (int j = 0; j < JN; j++) bfrag[j] = *(const s16x8*)&Bs[wn + j * 16 + l15][q * 8];
#pragma unroll
        for (int i = 0; i < 4; i++)
#pragma unroll
            for (int j = 0; j < JN; j++)
                acc[i][j] = __builtin_amdgcn_mfma_f32_16x16x32_bf16(af[i], bfrag[j], acc[i][j], 0, 0, 0);
    }

    // epilogue: C/D layout col=lane&15, row=quad*4+reg
#pragma unroll
    for (int i = 0; i < 4; i++) {
#pragma unroll
        for (int j = 0; j < JN; j++) {
            int n = bn + wn + j * 16 + l15;
            float bvv = bias ? __bfloat162float(bias[n]) : 0.f;
#pragma unroll
            for (int r = 0; r < 4; r++) {
                int m = bm + wm + i * 16 + q * 4 + r;
                float v = acc[i][j][r] + bvv;
                if (act) v = 0.5f * v * (1.f + erff(v * 0.70710678118f));
                if (res) v += __bfloat162float(res[(size_t)m * N + n]);
                size_t idx = (size_t)m * N + n;
                if (f32out) ((float*)C)[idx] = v;
                else        ((bf16*)C)[idx]  = __float2bfloat16(v);
            }
        }
    }
}

// ------------------------------ Attention ----------------------------------
// grid (S/64, B*H); 4 waves; wave = 16 q-rows, loops all t in 64-tiles.
// KV is the fused [B*S, 2048] buffer: K at col h*64, V at col 1024+h*64.
// St = K·Q^T (16x16x32 bf16): C layout == A layout of 16x16x16 f16 MFMA.
// Post-softmax mask => l is a pure sum; PV skipped for masked subs; V staging
// skipped for t0 < sblk. LDS XOR swizzles (16-elem chunks) as round 5.
__global__ __launch_bounds__(256)
void attn_kernel(const bf16* __restrict__ Q, const bf16* __restrict__ KV,
                 bf16* __restrict__ O)
{
    __shared__ alignas(16) short    Ks[64][72];   // [t][d'], swizzled cols
    __shared__ alignas(16) _Float16 Vs[64][72];   // [d][t'], swizzled cols

    const int tid  = threadIdx.x;
    const int lane = tid & 63;
    const int wave = tid >> 6;
    const int q    = lane >> 4;
    const int l15  = lane & 15;
    const int bh   = blockIdx.y;
    const int b    = bh >> 4, h = bh & 15;
    const int sblk   = blockIdx.x * 64;
    const int s_base = sblk + wave * 16;
    const int s_glob = s_base + l15;

    // Q as B-operand of K·Q^T: lane holds Q[s=lane&15][d=quad*8+j]
    const short* qrow = (const short*)Q + (size_t)(b * 2048 + s_glob) * 1024 + h * 64;
    s16x8 qf0 = *(const s16x8*)(qrow + q * 8);
    s16x8 qf1 = *(const s16x8*)(qrow + 32 + q * 8);

    float l_lane = 0.f;
    f32x4 o_acc[4] = {};

    const int trow   = tid >> 2;                        // t within tile, 0..63
    const int tchunk = tid & 3;                         // 16-elem d-chunk
    const int kswz   = (tchunk ^ (trow >> 2)) & 3;      // Ks write chunk
    const int vcol   = (((trow >> 4) ^ tchunk) & 3) * 16 + (trow & 15); // Vs col
    const int ksw    = l15 >> 2;                        // Ks read swizzle key

    for (int t0 = 0; t0 < 2048; t0 += 64) {
        const bool needV = (t0 >= sblk);
        const short* krow = (const short*)KV + (size_t)(b * 2048 + t0 + trow) * 2048 + h * 64;
        s16x8 k0 = *(const s16x8*)(krow + tchunk * 16);
        s16x8 k1 = *(const s16x8*)(krow + tchunk * 16 + 8);
        s16x8 v0, v1;
        if (needV) {
            const short* vrow = krow + 1024;
            v0 = *(const s16x8*)(vrow + tchunk * 16);
            v1 = *(const s16x8*)(vrow + tchunk * 16 + 8);
        }
        __syncthreads();
        *(s16x8*)&Ks[trow][kswz * 16]     = k0;
        *(s16x8*)&Ks[trow][kswz * 16 + 8] = k1;
        if (needV) {
#pragma unroll
            for (int e = 0; e < 8; e++) {
                Vs[tchunk * 16 + e][vcol]     = (_Float16)bfbits2f(v0[e]);
                Vs[tchunk * 16 + 8 + e][vcol] = (_Float16)bfbits2f(v1[e]);
            }
        }
        __syncthreads();

#pragma unroll
        for (int sub = 0; sub < 4; sub++) {
            const int tb  = sub * 16;
            const int rel = t0 + tb - s_base;   // wave-uniform
            s16x8 kf0 = *(const s16x8*)&Ks[tb + l15][(((q >> 1) ^ ksw) & 3) * 16 + (q & 1) * 8];
            s16x8 kf1 = *(const s16x8*)&Ks[tb + l15][((((q >> 1) + 2) ^ ksw) & 3) * 16 + (q & 1) * 8];
            f32x4 st = {};
            st = __builtin_amdgcn_mfma_f32_16x16x32_bf16(kf0, qf0, st, 0, 0, 0);
            st = __builtin_amdgcn_mfma_f32_16x16x32_bf16(kf1, qf1, st, 0, 0, 0);
            float p[4];
#pragma unroll
            for (int r = 0; r < 4; r++) {
                float sc = st[r] * 0.125f;
                p[r] = __expf(fminf(sc, 60.f));
                l_lane += p[r];
            }
            if (rel >= 0) {
                h16x4 pf;
                if (rel == 0) {
#pragma unroll
                    for (int r = 0; r < 4; r++)
                        pf[r] = (q * 4 + r > l15) ? (_Float16)p[r] : (_Float16)0.f;
                } else {
#pragma unroll
                    for (int r = 0; r < 4; r++) pf[r] = (_Float16)p[r];
                }
#pragma unroll
                for (int dt = 0; dt < 4; dt++) {
                    h16x4 vf = *(const h16x4*)&Vs[dt * 16 + l15]
                                                 [(((tb >> 4) ^ dt) & 3) * 16 + q * 4];
                    o_acc[dt] = __builtin_amdgcn_mfma_f32_16x16x16f16(pf, vf, o_acc[dt], 0, 0, 0);
                }
            }
        }
    }

    float l = l_lane;
    l += __shfl_xor(l, 16, 64);
    l += __shfl_xor(l, 32, 64);
    float linv[4];
#pragma unroll
    for (int r = 0; r < 4; r++) linv[r] = 1.f / __shfl(l, q * 4 + r, 64);
#pragma unroll
    for (int dt = 0; dt < 4; dt++)
#pragma unroll
        for (int r = 0; r < 4; r++) {
            int s = s_base + q * 4 + r;
            int d = dt * 16 + l15;
            O[(size_t)(b * 2048 + s) * 1024 + h * 64 + d] =
                __float2bfloat16(o_acc[dt][r] * linv[r]);
        }
}

// ------------------------------- launcher ----------------------------------
extern "C" void kernel_launch(void* const* d_in, const int* in_sizes, int n_in,
                              void* d_out, int out_size, void* d_ws, size_t ws_size,
                              hipStream_t stream)
{
    const void* x     = d_in[0];
    const void* y     = d_in[1];
    const void* Wq    = d_in[2];
    const void* Wk    = d_in[3];
    const void* Wv    = d_in[4];
    const void* li1_w = d_in[5];
    const void* li1_b = d_in[6];
    const void* ln1_w = d_in[7];
    const void* ln1_b = d_in[8];
    const void* ln2_w = d_in[9];
    const void* ln2_b = d_in[10];
    const void* ln3_w = d_in[11];
    const void* ln3_b = d_in[12];
    const void* li2_w = d_in[13];
    const void* li2_b = d_in[14];
    const void* li3_w = d_in[15];
    const void* li3_b = d_in[16];

    char* w = (char*)d_ws;
    const size_t MB = 1u << 20;
    bf16* xn    = (bf16*)(w + 0 * MB);
    bf16* yn    = (bf16*)(w + 8 * MB);
    bf16* WqT   = (bf16*)(w + 16 * MB);
    bf16* WkT   = (bf16*)(w + 18 * MB);   // WkT+WvT contiguous = fused KV weights
    bf16* WvT   = (bf16*)(w + 20 * MB);
    bf16* li1T  = (bf16*)(w + 22 * MB);
    bf16* li2T  = (bf16*)(w + 24 * MB);
    bf16* li3T  = (bf16*)(w + 32 * MB);
    bf16* xout  = (bf16*)(w + 40 * MB);
    bf16* Qb    = (bf16*)(w + 48 * MB);
    bf16* KVb   = (bf16*)(w + 56 * MB);   // [4096][2048], 16MB
    bf16* h2    = (bf16*)(w + 48 * MB);   // reuses Qb/KVb after attention
    bf16* xc    = (bf16*)(w + 80 * MB);   // canonical bf16 copy of x (residual)
    int*  flag  = (int*) (w + 88 * MB);
    bf16* li1bc = (bf16*)(w + 88 * MB + 4096);
    bf16* li2bc = (bf16*)(w + 88 * MB + 8192);
    bf16* li3bc = (bf16*)(w + 88 * MB + 24576);
    bf16* Ob    = yn;                     // reuse yn after KV projection
    bf16* hn    = xn;                     // reuse xn after Q projection

    // 0. dtype detection (deterministic per input -> graph-safe)
    detect_dtype<<<1, 256, 0, stream>>>((const short*)x, flag);

    // 1. canonical conversions
    conv_to_bf16<<<4096, 256, 0, stream>>>(x, xc, 4194304, flag);
    conv_to_bf16<<<1, 256, 0, stream>>>(li1_b, li1bc, 1024, flag);
    conv_to_bf16<<<4, 256, 0, stream>>>(li2_b, li2bc, 4096, flag);
    conv_to_bf16<<<1, 256, 0, stream>>>(li3_b, li3bc, 1024, flag);

    // 2. LayerNorms
    ln_kernel<<<4096, 256, 0, stream>>>(x, ln1_w, ln1_b, xn, flag, 0);
    ln_kernel<<<4096, 256, 0, stream>>>(y, ln2_w, ln2_b, yn, flag, 0);

    // 3. weight re-layouts (LDS-tiled, coalesced)
    pack_qkv_tiled<<<dim3(2, 32, 16), 256, 0, stream>>>(Wq, WqT, flag);
    pack_qkv_tiled<<<dim3(2, 32, 16), 256, 0, stream>>>(Wk, WkT, flag);
    pack_qkv_tiled<<<dim3(2, 32, 16), 256, 0, stream>>>(Wv, WvT, flag);
    transpose_tiled<<<dim3(32, 32),  256, 0, stream>>>(li1_w, li1T, 1024, 1024, flag);
    transpose_tiled<<<dim3(128, 32), 256, 0, stream>>>(li2_w, li2T, 1024, 4096, flag);
    transpose_tiled<<<dim3(32, 128), 256, 0, stream>>>(li3_w, li3T, 4096, 1024, flag);

    // 4. projections: Q (N=1024) and fused KV (N=2048)
    gemm_bt<64><<<dim3(32, 16), 256, 0, stream>>>(xn, WqT, nullptr, nullptr, Qb, 4096, 1024, 1024, 0, flag, 0);
    gemm_bt<64><<<dim3(32, 32), 256, 0, stream>>>(yn, WkT, nullptr, nullptr, KVb, 4096, 2048, 1024, 0, flag, 0);

    // 5. attention -> O [B,S,H*D]
    attn_kernel<<<dim3(32, 32), 256, 0, stream>>>(Qb, KVb, Ob);

    // 6. x_out = x + O @ li1_w + li1_b
    gemm_bt<64><<<dim3(32, 16), 256, 0, stream>>>(Ob, li1T, li1bc, xc, xout, 4096, 1024, 1024, 0, flag, 0);

    // 7. hn = LN3(x_out)
    ln_kernel<<<4096, 256, 0, stream>>>(xout, ln3_w, ln3_b, hn, flag, 1);

    // 8. h2 = gelu(hn @ li2_w + li2_b)
    gemm_bt<128><<<dim3(32, 32), 256, 0, stream>>>(hn, li2T, li2bc, nullptr, h2, 4096, 4096, 1024, 1, flag, 0);

    // 9. out = x_out + h2 @ li3_w + li3_b   (dtype-matched store)
    gemm_bt<64><<<dim3(32, 16), 256, 0, stream>>>(h2, li3T, li3bc, xout, d_out, 4096, 1024, 4096, 0, flag, 1);
}

// Round 7
// 524.574 us; speedup vs baseline: 1.3405x; 1.0352x over previous
//
#include <hip/hip_runtime.h>
#include <hip/hip_bf16.h>

// ---------------------------------------------------------------------------
// MultiHeadAttention block on MI355X (gfx950). Inputs float32 (device-detected,
// kept for robustness). Internal pipeline bf16 MFMA, fp32 accumulate.
// Round-7 changes (GEMM K-loop density):
//   * gemm_bt64: BN=64, BK=64 -> 16 MFMA/wave/barrier (was 8), half the
//     barriers. XOR chunk swizzle folded into the global_load_lds lane
//     mapping (write pattern is fixed lane->16B slots; we permute the GLOBAL
//     address per lane instead): LDS[r][c] = global chunk c^(r&7); frag
//     reads use key l15&7 -> 2 dwords/bank/phase = conflict-free.
//   * LN1 fused with the x->bf16 canonical copy; 3 bias convs in 1 launch.
//   * li2 keeps BN=128/BK=32 (BK=64 would blow VGPR at 4 waves/SIMD).
// Workspace (88MB + 32KB):
//   [0,8M) xn/hn  [8,16M) yn/O  [16,24M) WqT,WkT,WvT,li1T  [24,32M) li2T
//   [32,40M) li3T  [40,48M) xout  [48,56M) Qb  [56,72M) KVb
//   [48,80M) h2 (after attn)  [80,88M) xc  [88M) flag + biases
// ---------------------------------------------------------------------------

typedef __hip_bfloat16 bf16;
typedef __attribute__((ext_vector_type(8))) short  s16x8;
typedef __attribute__((ext_vector_type(4))) short  s16x4;
typedef __attribute__((ext_vector_type(4))) float  f32x4;
typedef __attribute__((ext_vector_type(4))) _Float16 h16x4;

__device__ __forceinline__ float bfbits2f(short s) {
    return __uint_as_float(((unsigned)(unsigned short)s) << 16);
}
__device__ __forceinline__ float load_in(const void* p, size_t i, int f32) {
    return f32 ? ((const float*)p)[i] : bfbits2f(((const short*)p)[i]);
}
// async global->LDS, 16B/lane; lds base wave-uniform, lane i -> base+16i
__device__ __forceinline__ void async16(const short* g, short* l) {
    __builtin_amdgcn_global_load_lds(
        (const __attribute__((address_space(1))) void*)g,
        (__attribute__((address_space(3))) void*)l, 16, 0, 0);
}

// ------------------------- dtype detection ---------------------------------
__global__ __launch_bounds__(256)
void detect_dtype(const short* __restrict__ x, int* __restrict__ flag)
{
    const int tid = threadIdx.x;
    int cnt = 0;
#pragma unroll
    for (int e = 0; e < 16; e++) {
        int idx = (tid * 16 + e) * 2;            // even shorts only
        int ex  = (x[idx] >> 7) & 0xFF;
        if (ex >= 113 && ex <= 142) cnt++;
    }
#pragma unroll
    for (int off = 1; off < 64; off <<= 1) cnt += __shfl_xor(cnt, off, 64);
    __shared__ int sh[4];
    if ((tid & 63) == 0) sh[tid >> 6] = cnt;
    __syncthreads();
    if (tid == 0) {
        int tot = sh[0] + sh[1] + sh[2] + sh[3];  // bf16: ~4096, f32: ~480
        flag[0] = (tot < 2458) ? 1 : 0;           // 1 == inputs are float32
    }
}

// --------------------- conversions / tiled transposes ----------------------
// all three linear biases in one launch (1024 + 4096 + 1024)
__global__ __launch_bounds__(256)
void conv_bias3(const void* b1, const void* b2, const void* b3,
                bf16* o1, bf16* o2, bf16* o3, const int* __restrict__ flag)
{
    const int f32 = flag[0];
    int i = blockIdx.x * 256 + threadIdx.x;      // 0..6143
    if (i < 1024)      o1[i]        = __float2bfloat16(load_in(b1, i, f32));
    else if (i < 5120) o2[i - 1024] = __float2bfloat16(load_in(b2, i - 1024, f32));
    else               o3[i - 5120] = __float2bfloat16(load_in(b3, i - 5120, f32));
}

// in [R,Cc] -> out [Cc,R], 32x32 LDS tiles, coalesced both sides
__global__ __launch_bounds__(256)
void transpose_tiled(const void* __restrict__ in, bf16* __restrict__ out,
                     int R, int Cc, const int* __restrict__ flag)
{
    __shared__ float tile[32][33];
    const int f32 = flag[0];
    const int tx = threadIdx.x & 31, ty = threadIdx.x >> 5;   // ty 0..7
    const int c0 = blockIdx.x * 32, r0 = blockIdx.y * 32;
#pragma unroll
    for (int i = 0; i < 4; i++)
        tile[ty + i * 8][tx] = load_in(in, (size_t)(r0 + ty + i * 8) * Cc + c0 + tx, f32);
    __syncthreads();
#pragma unroll
    for (int i = 0; i < 4; i++)
        out[(size_t)(c0 + ty + i * 8) * R + r0 + tx] = __float2bfloat16(tile[tx][ty + i * 8]);
}

// Wq [H][C=1024][D=64] -> WqT [H][D][C]  (per-head 1024x64 transpose)
__global__ __launch_bounds__(256)
void pack_qkv_tiled(const void* __restrict__ in, bf16* __restrict__ out,
                    const int* __restrict__ flag)
{
    __shared__ float tile[32][33];
    const int f32 = flag[0];
    const int tx = threadIdx.x & 31, ty = threadIdx.x >> 5;
    const int c0 = blockIdx.x * 32, r0 = blockIdx.y * 32;   // c: D, r: C
    const size_t base = (size_t)blockIdx.z * 1024 * 64;
#pragma unroll
    for (int i = 0; i < 4; i++)
        tile[ty + i * 8][tx] = load_in(in, base + (size_t)(r0 + ty + i * 8) * 64 + c0 + tx, f32);
    __syncthreads();
#pragma unroll
    for (int i = 0; i < 4; i++)
        out[base + (size_t)(c0 + ty + i * 8) * 1024 + r0 + tx] =
            __float2bfloat16(tile[tx][ty + i * 8]);
}

// ------------------------------- LayerNorm ---------------------------------
// optional copy_out: raw-value bf16 copy (fuses conv_to_bf16 of x into LN1)
__global__ __launch_bounds__(256)
void ln_kernel(const void* __restrict__ x, const void* __restrict__ w,
               const void* __restrict__ bv, bf16* __restrict__ out,
               const int* __restrict__ flag, int x_is_bf16,
               bf16* __restrict__ copy_out)
{
    const int f32  = flag[0];
    const int xf32 = x_is_bf16 ? 0 : f32;
    const int row  = blockIdx.x;
    const int tid  = threadIdx.x;
    const int lane = tid & 63;
    const int wave = tid >> 6;
    const size_t base = (size_t)row * 1024 + tid * 4;

    float v[4];
    float sum = 0.f, ss = 0.f;
#pragma unroll
    for (int e = 0; e < 4; e++) {
        v[e] = load_in(x, base + e, xf32);
        sum += v[e]; ss += v[e] * v[e];
    }
    if (copy_out) {
        s16x4 c;
#pragma unroll
        for (int e = 0; e < 4; e++) {
            __hip_bfloat16 hb = __float2bfloat16(v[e]);
            c[e] = *(short*)&hb;
        }
        *(s16x4*)((short*)copy_out + base) = c;
    }
#pragma unroll
    for (int off = 1; off < 64; off <<= 1) {
        sum += __shfl_xor(sum, off, 64);
        ss  += __shfl_xor(ss,  off, 64);
    }
    __shared__ float sh1[4], sh2[4];
    if (lane == 0) { sh1[wave] = sum; sh2[wave] = ss; }
    __syncthreads();
    float t1 = sh1[0] + sh1[1] + sh1[2] + sh1[3];
    float t2 = sh2[0] + sh2[1] + sh2[2] + sh2[3];
    float mu   = t1 * (1.f / 1024.f);
    float var  = t2 * (1.f / 1024.f) - mu * mu;
    float rstd = rsqrtf(var + 1e-5f);

#pragma unroll
    for (int e = 0; e < 4; e++) {
        float ov = (v[e] - mu) * rstd * load_in(w, tid * 4 + e, f32)
                 + load_in(bv, tid * 4 + e, f32);
        out[base + e] = __float2bfloat16(ov);
    }
}

// --------------------- GEMM 128xBNx32 (li2: BN=128) ------------------------
template<int BN>
__global__ __launch_bounds__(256)
void gemm_bt(const bf16* __restrict__ A, const bf16* __restrict__ Bt,
             const bf16* __restrict__ bias, const bf16* __restrict__ res,
             void* __restrict__ C, int M, int N, int K, int act,
             const int* __restrict__ dflag, int final_out)
{
    constexpr int JN = BN / 32;
    __shared__ alignas(16) short As[128][32];
    __shared__ alignas(16) short Bs[BN][32];

    const int f32out = final_out ? dflag[0] : 0;
    const int tid  = threadIdx.x;
    const int lane = tid & 63;
    const int wave = tid >> 6;
    const int q    = lane >> 4;
    const int l15  = lane & 15;
    const int wm   = (wave >> 1) * 64;
    const int wn   = (wave & 1) * (BN / 2);
    const int bm   = blockIdx.x * 128;
    const int bn   = blockIdx.y * BN;

    const int lr = lane >> 2;        // 0..15
    const int lc = (lane & 3) * 8;   // chunk

    f32x4 acc[4][JN] = {};

    const short* Abase = (const short*)A  + (size_t)(bm + wave * 32 + lr) * K + lc;
    const short* Bbase;
    if (BN == 128) Bbase = (const short*)Bt + (size_t)(bn + wave * 32 + lr) * K + lc;
    else           Bbase = (const short*)Bt + (size_t)(bn + wave * 16 + lr) * K + lc;

    for (int k0 = 0; k0 < K; k0 += 32) {
        __syncthreads();
        async16(Abase + k0,                  &As[wave * 32][0]);
        async16(Abase + k0 + (size_t)16 * K, &As[wave * 32 + 16][0]);
        if (BN == 128) {
            async16(Bbase + k0,                  &Bs[wave * 32][0]);
            async16(Bbase + k0 + (size_t)16 * K, &Bs[wave * 32 + 16][0]);
        } else {
            async16(Bbase + k0, &Bs[wave * 16][0]);
        }
        __syncthreads();

        s16x8 af[4], bfrag[JN];
#pragma unroll
        for (int i = 0; i < 4; i++)  af[i]    = *(const s16x8*)&As[wm + i * 16 + l15][q * 8];
#pragma unroll
        for (int j = 0; j < JN; j++) bfrag[j] = *(const s16x8*)&Bs[wn + j * 16 + l15][q * 8];
#pragma unroll
        for (int i = 0; i < 4; i++)
#pragma unroll
            for (int j = 0; j < JN; j++)
                acc[i][j] = __builtin_amdgcn_mfma_f32_16x16x32_bf16(af[i], bfrag[j], acc[i][j], 0, 0, 0);
    }

#pragma unroll
    for (int i = 0; i < 4; i++) {
#pragma unroll
        for (int j = 0; j < JN; j++) {
            int n = bn + wn + j * 16 + l15;
            float bvv = bias ? __bfloat162float(bias[n]) : 0.f;
#pragma unroll
            for (int r = 0; r < 4; r++) {
                int m = bm + wm + i * 16 + q * 4 + r;
                float v = acc[i][j][r] + bvv;
                if (act) v = 0.5f * v * (1.f + erff(v * 0.70710678118f));
                if (res) v += __bfloat162float(res[(size_t)m * N + n]);
                size_t idx = (size_t)m * N + n;
                if (f32out) ((float*)C)[idx] = v;
                else        ((bf16*)C)[idx]  = __float2bfloat16(v);
            }
        }
    }
}

// ------------------- GEMM 128x64x64, swizzled staging ----------------------
// 16 MFMA/wave/barrier; LDS[r][c] holds global chunk c^(r&7) (8-short chunks)
// via per-lane global address permutation; frag reads use key l15&7 ->
// 2 dwords/bank/phase (conflict-free).
__global__ __launch_bounds__(256)
void gemm_bt64(const bf16* __restrict__ A, const bf16* __restrict__ Bt,
               const bf16* __restrict__ bias, const bf16* __restrict__ res,
               void* __restrict__ C, int M, int N, int K, int act,
               const int* __restrict__ dflag, int final_out)
{
    __shared__ alignas(16) short As[128][64];
    __shared__ alignas(16) short Bs[64][64];

    const int f32out = final_out ? dflag[0] : 0;
    const int tid  = threadIdx.x;
    const int lane = tid & 63;
    const int wave = tid >> 6;
    const int q    = lane >> 4;
    const int l15  = lane & 15;
    const int wm   = (wave >> 1) * 64;
    const int wn   = (wave & 1) * 32;
    const int bm   = blockIdx.x * 128;
    const int bn   = blockIdx.y * 64;

    const int srow   = lane >> 3;              // 0..7 within octet
    const int gchunk = (lane & 7) ^ srow;      // permuted global chunk
    const short* Ab = (const short*)A  + (size_t)(bm + wave * 32 + srow) * K + gchunk * 8;
    const short* Bb = (const short*)Bt + (size_t)(bn + wave * 16 + srow) * K + gchunk * 8;
    const int csw = l15 & 7;                   // frag-read swizzle key

    f32x4 acc[4][2] = {};

    for (int k0 = 0; k0 < K; k0 += 64) {
        __syncthreads();
        async16(Ab + k0,                  &As[wave * 32][0]);
        async16(Ab + k0 + (size_t)8  * K, &As[wave * 32 + 8][0]);
        async16(Ab + k0 + (size_t)16 * K, &As[wave * 32 + 16][0]);
        async16(Ab + k0 + (size_t)24 * K, &As[wave * 32 + 24][0]);
        async16(Bb + k0,                  &Bs[wave * 16][0]);
        async16(Bb + k0 + (size_t)8  * K, &Bs[wave * 16 + 8][0]);
        __syncthreads();

        s16x8 af[4][2], bfr[2][2];
#pragma unroll
        for (int i = 0; i < 4; i++)
#pragma unroll
            for (int kk = 0; kk < 2; kk++)
                af[i][kk] = *(const s16x8*)&As[wm + i * 16 + l15][((kk * 4 + q) ^ csw) * 8];
#pragma unroll
        for (int j = 0; j < 2; j++)
#pragma unroll
            for (int kk = 0; kk < 2; kk++)
                bfr[j][kk] = *(const s16x8*)&Bs[wn + j * 16 + l15][((kk * 4 + q) ^ csw) * 8];
#pragma unroll
        for (int i = 0; i < 4; i++)
#pragma unroll
            for (int j = 0; j < 2; j++) {
                acc[i][j] = __builtin_amdgcn_mfma_f32_16x16x32_bf16(af[i][0], bfr[j][0], acc[i][j], 0, 0, 0);
                acc[i][j] = __builtin_amdgcn_mfma_f32_16x16x32_bf16(af[i][1], bfr[j][1], acc[i][j], 0, 0, 0);
            }
    }

#pragma unroll
    for (int i = 0; i < 4; i++) {
#pragma unroll
        for (int j = 0; j < 2; j++) {
            int n = bn + wn + j * 16 + l15;
            float bvv = bias ? __bfloat162float(bias[n]) : 0.f;
#pragma unroll
            for (int r = 0; r < 4; r++) {
                int m = bm + wm + i * 16 + q * 4 + r;
                float v = acc[i][j][r] + bvv;
                if (act) v = 0.5f * v * (1.f + erff(v * 0.70710678118f));
                if (res) v += __bfloat162float(res[(size_t)m * N + n]);
                size_t idx = (size_t)m * N + n;
                if (f32out) ((float*)C)[idx] = v;
                else        ((bf16*)C)[idx]  = __float2bfloat16(v);
            }
        }
    }
}

// ------------------------------ Attention ----------------------------------
// grid (S/64, B*H); 4 waves; wave = 16 q-rows, loops all t in 64-tiles.
// KV fused [B*S, 2048]: K at col h*64, V at col 1024+h*64.
// St = K·Q^T (16x16x32 bf16): C layout == A layout of 16x16x16 f16 MFMA.
// Post-softmax mask => l is a pure sum; PV skipped for masked subs; V staging
// skipped for t0 < sblk. LDS XOR swizzles (16-elem chunks).
__global__ __launch_bounds__(256)
void attn_kernel(const bf16* __restrict__ Q, const bf16* __restrict__ KV,
                 bf16* __restrict__ O)
{
    __shared__ alignas(16) short    Ks[64][72];   // [t][d'], swizzled cols
    __shared__ alignas(16) _Float16 Vs[64][72];   // [d][t'], swizzled cols

    const int tid  = threadIdx.x;
    const int lane = tid & 63;
    const int wave = tid >> 6;
    const int q    = lane >> 4;
    const int l15  = lane & 15;
    const int bh   = blockIdx.y;
    const int b    = bh >> 4, h = bh & 15;
    const int sblk   = blockIdx.x * 64;
    const int s_base = sblk + wave * 16;
    const int s_glob = s_base + l15;

    const short* qrow = (const short*)Q + (size_t)(b * 2048 + s_glob) * 1024 + h * 64;
    s16x8 qf0 = *(const s16x8*)(qrow + q * 8);
    s16x8 qf1 = *(const s16x8*)(qrow + 32 + q * 8);

    float l_lane = 0.f;
    f32x4 o_acc[4] = {};

    const int trow   = tid >> 2;
    const int tchunk = tid & 3;
    const int kswz   = (tchunk ^ (trow >> 2)) & 3;
    const int vcol   = (((trow >> 4) ^ tchunk) & 3) * 16 + (trow & 15);
    const int ksw    = l15 >> 2;

    for (int t0 = 0; t0 < 2048; t0 += 64) {
        const bool needV = (t0 >= sblk);
        const short* krow = (const short*)KV + (size_t)(b * 2048 + t0 + trow) * 2048 + h * 64;
        s16x8 k0 = *(const s16x8*)(krow + tchunk * 16);
        s16x8 k1 = *(const s16x8*)(krow + tchunk * 16 + 8);
        s16x8 v0, v1;
        if (needV) {
            const short* vrow = krow + 1024;
            v0 = *(const s16x8*)(vrow + tchunk * 16);
            v1 = *(const s16x8*)(vrow + tchunk * 16 + 8);
        }
        __syncthreads();
        *(s16x8*)&Ks[trow][kswz * 16]     = k0;
        *(s16x8*)&Ks[trow][kswz * 16 + 8] = k1;
        if (needV) {
#pragma unroll
            for (int e = 0; e < 8; e++) {
                Vs[tchunk * 16 + e][vcol]     = (_Float16)bfbits2f(v0[e]);
                Vs[tchunk * 16 + 8 + e][vcol] = (_Float16)bfbits2f(v1[e]);
            }
        }
        __syncthreads();

#pragma unroll
        for (int sub = 0; sub < 4; sub++) {
            const int tb  = sub * 16;
            const int rel = t0 + tb - s_base;
            s16x8 kf0 = *(const s16x8*)&Ks[tb + l15][(((q >> 1) ^ ksw) & 3) * 16 + (q & 1) * 8];
            s16x8 kf1 = *(const s16x8*)&Ks[tb + l15][((((q >> 1) + 2) ^ ksw) & 3) * 16 + (q & 1) * 8];
            f32x4 st = {};
            st = __builtin_amdgcn_mfma_f32_16x16x32_bf16(kf0, qf0, st, 0, 0, 0);
            st = __builtin_amdgcn_mfma_f32_16x16x32_bf16(kf1, qf1, st, 0, 0, 0);
            float p[4];
#pragma unroll
            for (int r = 0; r < 4; r++) {
                float sc = st[r] * 0.125f;
                p[r] = __expf(fminf(sc, 60.f));
                l_lane += p[r];
            }
            if (rel >= 0) {
                h16x4 pf;
                if (rel == 0) {
#pragma unroll
                    for (int r = 0; r < 4; r++)
                        pf[r] = (q * 4 + r > l15) ? (_Float16)p[r] : (_Float16)0.f;
                } else {
#pragma unroll
                    for (int r = 0; r < 4; r++) pf[r] = (_Float16)p[r];
                }
#pragma unroll
                for (int dt = 0; dt < 4; dt++) {
                    h16x4 vf = *(const h16x4*)&Vs[dt * 16 + l15]
                                                 [(((tb >> 4) ^ dt) & 3) * 16 + q * 4];
                    o_acc[dt] = __builtin_amdgcn_mfma_f32_16x16x16f16(pf, vf, o_acc[dt], 0, 0, 0);
                }
            }
        }
    }

    float l = l_lane;
    l += __shfl_xor(l, 16, 64);
    l += __shfl_xor(l, 32, 64);
    float linv[4];
#pragma unroll
    for (int r = 0; r < 4; r++) linv[r] = 1.f / __shfl(l, q * 4 + r, 64);
#pragma unroll
    for (int dt = 0; dt < 4; dt++)
#pragma unroll
        for (int r = 0; r < 4; r++) {
            int s = s_base + q * 4 + r;
            int d = dt * 16 + l15;
            O[(size_t)(b * 2048 + s) * 1024 + h * 64 + d] =
                __float2bfloat16(o_acc[dt][r] * linv[r]);
        }
}

// ------------------------------- launcher ----------------------------------
extern "C" void kernel_launch(void* const* d_in, const int* in_sizes, int n_in,
                              void* d_out, int out_size, void* d_ws, size_t ws_size,
                              hipStream_t stream)
{
    const void* x     = d_in[0];
    const void* y     = d_in[1];
    const void* Wq    = d_in[2];
    const void* Wk    = d_in[3];
    const void* Wv    = d_in[4];
    const void* li1_w = d_in[5];
    const void* li1_b = d_in[6];
    const void* ln1_w = d_in[7];
    const void* ln1_b = d_in[8];
    const void* ln2_w = d_in[9];
    const void* ln2_b = d_in[10];
    const void* ln3_w = d_in[11];
    const void* ln3_b = d_in[12];
    const void* li2_w = d_in[13];
    const void* li2_b = d_in[14];
    const void* li3_w = d_in[15];
    const void* li3_b = d_in[16];

    char* w = (char*)d_ws;
    const size_t MB = 1u << 20;
    bf16* xn    = (bf16*)(w + 0 * MB);
    bf16* yn    = (bf16*)(w + 8 * MB);
    bf16* WqT   = (bf16*)(w + 16 * MB);
    bf16* WkT   = (bf16*)(w + 18 * MB);   // WkT+WvT contiguous = fused KV weights
    bf16* WvT   = (bf16*)(w + 20 * MB);
    bf16* li1T  = (bf16*)(w + 22 * MB);
    bf16* li2T  = (bf16*)(w + 24 * MB);
    bf16* li3T  = (bf16*)(w + 32 * MB);
    bf16* xout  = (bf16*)(w + 40 * MB);
    bf16* Qb    = (bf16*)(w + 48 * MB);
    bf16* KVb   = (bf16*)(w + 56 * MB);   // [4096][2048], 16MB
    bf16* h2    = (bf16*)(w + 48 * MB);   // reuses Qb/KVb after attention
    bf16* xc    = (bf16*)(w + 80 * MB);   // canonical bf16 copy of x (residual)
    int*  flag  = (int*) (w + 88 * MB);
    bf16* li1bc = (bf16*)(w + 88 * MB + 4096);
    bf16* li2bc = (bf16*)(w + 88 * MB + 8192);
    bf16* li3bc = (bf16*)(w + 88 * MB + 24576);
    bf16* Ob    = yn;                     // reuse yn after KV projection
    bf16* hn    = xn;                     // reuse xn after Q projection

    // 0. dtype detection (deterministic per input -> graph-safe)
    detect_dtype<<<1, 256, 0, stream>>>((const short*)x, flag);

    // 1. biases (single launch)
    conv_bias3<<<24, 256, 0, stream>>>(li1_b, li2_b, li3_b, li1bc, li2bc, li3bc, flag);

    // 2. LayerNorms (LN1 also emits the canonical bf16 copy of x)
    ln_kernel<<<4096, 256, 0, stream>>>(x, ln1_w, ln1_b, xn, flag, 0, xc);
    ln_kernel<<<4096, 256, 0, stream>>>(y, ln2_w, ln2_b, yn, flag, 0, nullptr);

    // 3. weight re-layouts (LDS-tiled, coalesced)
    pack_qkv_tiled<<<dim3(2, 32, 16), 256, 0, stream>>>(Wq, WqT, flag);
    pack_qkv_tiled<<<dim3(2, 32, 16), 256, 0, stream>>>(Wk, WkT, flag);
    pack_qkv_tiled<<<dim3(2, 32, 16), 256, 0, stream>>>(Wv, WvT, flag);
    transpose_tiled<<<dim3(32, 32),  256, 0, stream>>>(li1_w, li1T, 1024, 1024, flag);
    transpose_tiled<<<dim3(128, 32), 256, 0, stream>>>(li2_w, li2T, 1024, 4096, flag);
    transpose_tiled<<<dim3(32, 128), 256, 0, stream>>>(li3_w, li3T, 4096, 1024, flag);

    // 4. projections: Q (N=1024) and fused KV (N=2048)
    gemm_bt64<<<dim3(32, 16), 256, 0, stream>>>(xn, WqT, nullptr, nullptr, Qb, 4096, 1024, 1024, 0, flag, 0);
    gemm_bt64<<<dim3(32, 32), 256, 0, stream>>>(yn, WkT, nullptr, nullptr, KVb, 4096, 2048, 1024, 0, flag, 0);

    // 5. attention -> O [B,S,H*D]
    attn_kernel<<<dim3(32, 32), 256, 0, stream>>>(Qb, KVb, Ob);

    // 6. x_out = x + O @ li1_w + li1_b
    gemm_bt64<<<dim3(32, 16), 256, 0, stream>>>(Ob, li1T, li1bc, xc, xout, 4096, 1024, 1024, 0, flag, 0);

    // 7. hn = LN3(x_out)
    ln_kernel<<<4096, 256, 0, stream>>>(xout, ln3_w, ln3_b, hn, flag, 1, nullptr);

    // 8. h2 = gelu(hn @ li2_w + li2_b)
    gemm_bt<128><<<dim3(32, 32), 256, 0, stream>>>(hn, li2T, li2bc, nullptr, h2, 4096, 4096, 1024, 1, flag, 0);

    // 9. out = x_out + h2 @ li3_w + li3_b   (dtype-matched store)
    gemm_bt64<<<dim3(32, 16), 256, 0, stream>>>(h2, li3T, li3bc, xout, d_out, 4096, 1024, 4096, 0, flag, 1);
}

// Round 8
// 502.585 us; speedup vs baseline: 1.3992x; 1.0437x over previous
//
#include <hip/hip_runtime.h>
#include <hip/hip_bf16.h>

// ---------------------------------------------------------------------------
// MultiHeadAttention block on MI355X (gfx950). Inputs float32 (device-detected,
// kept for robustness). Internal pipeline bf16 MFMA, fp32 accumulate.
// Round-8 changes (attention staging + li2):
//   * V pre-transposed to Vt[b][h*64+d][t] (f16) by a tiled kernel ->
//     attention stages BOTH K and V via global_load_lds width=16 into
//     unpadded [64][64] LDS tiles with per-lane global-chunk XOR permutation
//     (gch=(lane&7)^srow, read key l15&7). Kills the 16 scalar cvt+ds_write_b16
//     per thread/tile V transpose and the K VGPR round-trip (VALUBusy 54%).
//   * li2 GEMM -> BN=128, BK=64, swizzled async staging (32 MFMA/wave/barrier),
//     replacing the unswizzled BK=32 version (8-way frag-read aliasing).
// Workspace (88MB + 32KB):
//   [0,8M) xn/hn  [8,16M) yn/O  [16,24M) WqT,WkT,WvT,li1T  [24,32M) li2T
//   [32,40M) li3T  [40,48M) xout  [48,56M) Qb  [56,72M) KVb  [72,80M) Vt
//   [48,80M) h2 (after attn)  [80,88M) xc  [88M) flag + biases
// ---------------------------------------------------------------------------

typedef __hip_bfloat16 bf16;
typedef __attribute__((ext_vector_type(8))) short  s16x8;
typedef __attribute__((ext_vector_type(4))) short  s16x4;
typedef __attribute__((ext_vector_type(4))) float  f32x4;
typedef __attribute__((ext_vector_type(4))) _Float16 h16x4;

__device__ __forceinline__ float bfbits2f(short s) {
    return __uint_as_float(((unsigned)(unsigned short)s) << 16);
}
__device__ __forceinline__ float load_in(const void* p, size_t i, int f32) {
    return f32 ? ((const float*)p)[i] : bfbits2f(((const short*)p)[i]);
}
// async global->LDS, 16B/lane; lds base wave-uniform, lane i -> base+16i
__device__ __forceinline__ void async16(const short* g, short* l) {
    __builtin_amdgcn_global_load_lds(
        (const __attribute__((address_space(1))) void*)g,
        (__attribute__((address_space(3))) void*)l, 16, 0, 0);
}

// ------------------------- dtype detection ---------------------------------
__global__ __launch_bounds__(256)
void detect_dtype(const short* __restrict__ x, int* __restrict__ flag)
{
    const int tid = threadIdx.x;
    int cnt = 0;
#pragma unroll
    for (int e = 0; e < 16; e++) {
        int idx = (tid * 16 + e) * 2;            // even shorts only
        int ex  = (x[idx] >> 7) & 0xFF;
        if (ex >= 113 && ex <= 142) cnt++;
    }
#pragma unroll
    for (int off = 1; off < 64; off <<= 1) cnt += __shfl_xor(cnt, off, 64);
    __shared__ int sh[4];
    if ((tid & 63) == 0) sh[tid >> 6] = cnt;
    __syncthreads();
    if (tid == 0) {
        int tot = sh[0] + sh[1] + sh[2] + sh[3];  // bf16: ~4096, f32: ~480
        flag[0] = (tot < 2458) ? 1 : 0;           // 1 == inputs are float32
    }
}

// --------------------- conversions / tiled transposes ----------------------
__global__ __launch_bounds__(256)
void conv_bias3(const void* b1, const void* b2, const void* b3,
                bf16* o1, bf16* o2, bf16* o3, const int* __restrict__ flag)
{
    const int f32 = flag[0];
    int i = blockIdx.x * 256 + threadIdx.x;      // 0..6143
    if (i < 1024)      o1[i]        = __float2bfloat16(load_in(b1, i, f32));
    else if (i < 5120) o2[i - 1024] = __float2bfloat16(load_in(b2, i - 1024, f32));
    else               o3[i - 5120] = __float2bfloat16(load_in(b3, i - 5120, f32));
}

// in [R,Cc] -> out [Cc,R], 32x32 LDS tiles, coalesced both sides
__global__ __launch_bounds__(256)
void transpose_tiled(const void* __restrict__ in, bf16* __restrict__ out,
                     int R, int Cc, const int* __restrict__ flag)
{
    __shared__ float tile[32][33];
    const int f32 = flag[0];
    const int tx = threadIdx.x & 31, ty = threadIdx.x >> 5;   // ty 0..7
    const int c0 = blockIdx.x * 32, r0 = blockIdx.y * 32;
#pragma unroll
    for (int i = 0; i < 4; i++)
        tile[ty + i * 8][tx] = load_in(in, (size_t)(r0 + ty + i * 8) * Cc + c0 + tx, f32);
    __syncthreads();
#pragma unroll
    for (int i = 0; i < 4; i++)
        out[(size_t)(c0 + ty + i * 8) * R + r0 + tx] = __float2bfloat16(tile[tx][ty + i * 8]);
}

// Wq [H][C=1024][D=64] -> WqT [H][D][C]  (per-head 1024x64 transpose)
__global__ __launch_bounds__(256)
void pack_qkv_tiled(const void* __restrict__ in, bf16* __restrict__ out,
                    const int* __restrict__ flag)
{
    __shared__ float tile[32][33];
    const int f32 = flag[0];
    const int tx = threadIdx.x & 31, ty = threadIdx.x >> 5;
    const int c0 = blockIdx.x * 32, r0 = blockIdx.y * 32;   // c: D, r: C
    const size_t base = (size_t)blockIdx.z * 1024 * 64;
#pragma unroll
    for (int i = 0; i < 4; i++)
        tile[ty + i * 8][tx] = load_in(in, base + (size_t)(r0 + ty + i * 8) * 64 + c0 + tx, f32);
    __syncthreads();
#pragma unroll
    for (int i = 0; i < 4; i++)
        out[base + (size_t)(c0 + ty + i * 8) * 1024 + r0 + tx] =
            __float2bfloat16(tile[tx][ty + i * 8]);
}

// V part of KVb [b][t][1024+hd] -> Vt [b][hd][t] as f16
__global__ __launch_bounds__(256)
void v_transpose(const bf16* __restrict__ KV, _Float16* __restrict__ Vt)
{
    __shared__ short tile[32][33];
    const int tx = threadIdx.x & 31, ty = threadIdx.x >> 5;
    const int t0 = blockIdx.x * 32, hd0 = blockIdx.y * 32, b = blockIdx.z;
#pragma unroll
    for (int i = 0; i < 4; i++)
        tile[ty + i * 8][tx] =
            ((const short*)KV)[(size_t)(b * 2048 + t0 + ty + i * 8) * 2048 + 1024 + hd0 + tx];
    __syncthreads();
#pragma unroll
    for (int i = 0; i < 4; i++)
        Vt[(size_t)(b * 1024 + hd0 + ty + i * 8) * 2048 + t0 + tx] =
            (_Float16)bfbits2f(tile[tx][ty + i * 8]);
}

// ------------------------------- LayerNorm ---------------------------------
__global__ __launch_bounds__(256)
void ln_kernel(const void* __restrict__ x, const void* __restrict__ w,
               const void* __restrict__ bv, bf16* __restrict__ out,
               const int* __restrict__ flag, int x_is_bf16,
               bf16* __restrict__ copy_out)
{
    const int f32  = flag[0];
    const int xf32 = x_is_bf16 ? 0 : f32;
    const int row  = blockIdx.x;
    const int tid  = threadIdx.x;
    const int lane = tid & 63;
    const int wave = tid >> 6;
    const size_t base = (size_t)row * 1024 + tid * 4;

    float v[4];
    float sum = 0.f, ss = 0.f;
#pragma unroll
    for (int e = 0; e < 4; e++) {
        v[e] = load_in(x, base + e, xf32);
        sum += v[e]; ss += v[e] * v[e];
    }
    if (copy_out) {
        s16x4 c;
#pragma unroll
        for (int e = 0; e < 4; e++) {
            __hip_bfloat16 hb = __float2bfloat16(v[e]);
            c[e] = *(short*)&hb;
        }
        *(s16x4*)((short*)copy_out + base) = c;
    }
#pragma unroll
    for (int off = 1; off < 64; off <<= 1) {
        sum += __shfl_xor(sum, off, 64);
        ss  += __shfl_xor(ss,  off, 64);
    }
    __shared__ float sh1[4], sh2[4];
    if (lane == 0) { sh1[wave] = sum; sh2[wave] = ss; }
    __syncthreads();
    float t1 = sh1[0] + sh1[1] + sh1[2] + sh1[3];
    float t2 = sh2[0] + sh2[1] + sh2[2] + sh2[3];
    float mu   = t1 * (1.f / 1024.f);
    float var  = t2 * (1.f / 1024.f) - mu * mu;
    float rstd = rsqrtf(var + 1e-5f);

#pragma unroll
    for (int e = 0; e < 4; e++) {
        float ov = (v[e] - mu) * rstd * load_in(w, tid * 4 + e, f32)
                 + load_in(bv, tid * 4 + e, f32);
        out[base + e] = __float2bfloat16(ov);
    }
}

// ------------------- GEMM 128x64x64, swizzled staging ----------------------
__global__ __launch_bounds__(256)
void gemm_bt64(const bf16* __restrict__ A, const bf16* __restrict__ Bt,
               const bf16* __restrict__ bias, const bf16* __restrict__ res,
               void* __restrict__ C, int M, int N, int K, int act,
               const int* __restrict__ dflag, int final_out)
{
    __shared__ alignas(16) short As[128][64];
    __shared__ alignas(16) short Bs[64][64];

    const int f32out = final_out ? dflag[0] : 0;
    const int tid  = threadIdx.x;
    const int lane = tid & 63;
    const int wave = tid >> 6;
    const int q    = lane >> 4;
    const int l15  = lane & 15;
    const int wm   = (wave >> 1) * 64;
    const int wn   = (wave & 1) * 32;
    const int bm   = blockIdx.x * 128;
    const int bn   = blockIdx.y * 64;

    const int srow   = lane >> 3;              // 0..7
    const int gchunk = (lane & 7) ^ srow;      // permuted global chunk
    const short* Ab = (const short*)A  + (size_t)(bm + wave * 32 + srow) * K + gchunk * 8;
    const short* Bb = (const short*)Bt + (size_t)(bn + wave * 16 + srow) * K + gchunk * 8;
    const int csw = l15 & 7;

    f32x4 acc[4][2] = {};

    for (int k0 = 0; k0 < K; k0 += 64) {
        __syncthreads();
        async16(Ab + k0,                  &As[wave * 32][0]);
        async16(Ab + k0 + (size_t)8  * K, &As[wave * 32 + 8][0]);
        async16(Ab + k0 + (size_t)16 * K, &As[wave * 32 + 16][0]);
        async16(Ab + k0 + (size_t)24 * K, &As[wave * 32 + 24][0]);
        async16(Bb + k0,                  &Bs[wave * 16][0]);
        async16(Bb + k0 + (size_t)8  * K, &Bs[wave * 16 + 8][0]);
        __syncthreads();

        s16x8 af[4][2], bfr[2][2];
#pragma unroll
        for (int i = 0; i < 4; i++)
#pragma unroll
            for (int kk = 0; kk < 2; kk++)
                af[i][kk] = *(const s16x8*)&As[wm + i * 16 + l15][((kk * 4 + q) ^ csw) * 8];
#pragma unroll
        for (int j = 0; j < 2; j++)
#pragma unroll
            for (int kk = 0; kk < 2; kk++)
                bfr[j][kk] = *(const s16x8*)&Bs[wn + j * 16 + l15][((kk * 4 + q) ^ csw) * 8];
#pragma unroll
        for (int i = 0; i < 4; i++)
#pragma unroll
            for (int j = 0; j < 2; j++) {
                acc[i][j] = __builtin_amdgcn_mfma_f32_16x16x32_bf16(af[i][0], bfr[j][0], acc[i][j], 0, 0, 0);
                acc[i][j] = __builtin_amdgcn_mfma_f32_16x16x32_bf16(af[i][1], bfr[j][1], acc[i][j], 0, 0, 0);
            }
    }

#pragma unroll
    for (int i = 0; i < 4; i++) {
#pragma unroll
        for (int j = 0; j < 2; j++) {
            int n = bn + wn + j * 16 + l15;
            float bvv = bias ? __bfloat162float(bias[n]) : 0.f;
#pragma unroll
            for (int r = 0; r < 4; r++) {
                int m = bm + wm + i * 16 + q * 4 + r;
                float v = acc[i][j][r] + bvv;
                if (act) v = 0.5f * v * (1.f + erff(v * 0.70710678118f));
                if (res) v += __bfloat162float(res[(size_t)m * N + n]);
                size_t idx = (size_t)m * N + n;
                if (f32out) ((float*)C)[idx] = v;
                else        ((bf16*)C)[idx]  = __float2bfloat16(v);
            }
        }
    }
}

// ------------------- GEMM 128x128x64, swizzled staging (li2) ---------------
__global__ __launch_bounds__(256)
void gemm_bt128(const bf16* __restrict__ A, const bf16* __restrict__ Bt,
                const bf16* __restrict__ bias, const bf16* __restrict__ res,
                void* __restrict__ C, int M, int N, int K, int act,
                const int* __restrict__ dflag, int final_out)
{
    __shared__ alignas(16) short As[128][64];
    __shared__ alignas(16) short Bs[128][64];

    const int f32out = final_out ? dflag[0] : 0;
    const int tid  = threadIdx.x;
    const int lane = tid & 63;
    const int wave = tid >> 6;
    const int q    = lane >> 4;
    const int l15  = lane & 15;
    const int wm   = (wave >> 1) * 64;
    const int wn   = (wave & 1) * 64;
    const int bm   = blockIdx.x * 128;
    const int bn   = blockIdx.y * 128;

    const int srow   = lane >> 3;
    const int gchunk = (lane & 7) ^ srow;
    const short* Ab = (const short*)A  + (size_t)(bm + wave * 32 + srow) * K + gchunk * 8;
    const short* Bb = (const short*)Bt + (size_t)(bn + wave * 32 + srow) * K + gchunk * 8;
    const int csw = l15 & 7;

    f32x4 acc[4][4] = {};

    for (int k0 = 0; k0 < K; k0 += 64) {
        __syncthreads();
#pragma unroll
        for (int r8 = 0; r8 < 4; r8++) {
            async16(Ab + k0 + (size_t)(r8 * 8) * K, &As[wave * 32 + r8 * 8][0]);
            async16(Bb + k0 + (size_t)(r8 * 8) * K, &Bs[wave * 32 + r8 * 8][0]);
        }
        __syncthreads();

#pragma unroll
        for (int kk = 0; kk < 2; kk++) {
            s16x8 af[4], bfr[4];
#pragma unroll
            for (int i = 0; i < 4; i++) af[i]  = *(const s16x8*)&As[wm + i * 16 + l15][((kk * 4 + q) ^ csw) * 8];
#pragma unroll
            for (int j = 0; j < 4; j++) bfr[j] = *(const s16x8*)&Bs[wn + j * 16 + l15][((kk * 4 + q) ^ csw) * 8];
#pragma unroll
            for (int i = 0; i < 4; i++)
#pragma unroll
                for (int j = 0; j < 4; j++)
                    acc[i][j] = __builtin_amdgcn_mfma_f32_16x16x32_bf16(af[i], bfr[j], acc[i][j], 0, 0, 0);
        }
    }

#pragma unroll
    for (int i = 0; i < 4; i++) {
#pragma unroll
        for (int j = 0; j < 4; j++) {
            int n = bn + wn + j * 16 + l15;
            float bvv = bias ? __bfloat162float(bias[n]) : 0.f;
#pragma unroll
            for (int r = 0; r < 4; r++) {
                int m = bm + wm + i * 16 + q * 4 + r;
                float v = acc[i][j][r] + bvv;
                if (act) v = 0.5f * v * (1.f + erff(v * 0.70710678118f));
                if (res) v += __bfloat162float(res[(size_t)m * N + n]);
                size_t idx = (size_t)m * N + n;
                if (f32out) ((float*)C)[idx] = v;
                else        ((bf16*)C)[idx]  = __float2bfloat16(v);
            }
        }
    }
}

// ------------------------------ Attention ----------------------------------
// grid (S/64, B*H); 4 waves; wave = 16 q-rows, loops all t in 64-tiles.
// K from fused KVb (col h*64); V from pre-transposed Vt[b][h*64+d][t] (f16).
// Both staged via global_load_lds w16 into unpadded [64][64] tiles, global
// chunk permuted per lane: LDS[row][c] = global[row][c ^ (row&7)].
// St = K·Q^T (16x16x32 bf16): C layout == A layout of 16x16x16 f16 MFMA.
// Post-softmax mask => l is a pure sum; PV skipped for masked subs; V staging
// skipped for t0 < sblk.
__global__ __launch_bounds__(256)
void attn_kernel(const bf16* __restrict__ Q, const bf16* __restrict__ KV,
                 const _Float16* __restrict__ Vt, bf16* __restrict__ O)
{
    __shared__ alignas(16) short    Ks[64][64];   // [t][d'], chunk-swizzled
    __shared__ alignas(16) _Float16 Vs[64][64];   // [d][t'], chunk-swizzled

    const int tid  = threadIdx.x;
    const int lane = tid & 63;
    const int wave = tid >> 6;
    const int q    = lane >> 4;
    const int l15  = lane & 15;
    const int bh   = blockIdx.y;
    const int b    = bh >> 4, h = bh & 15;
    const int sblk   = blockIdx.x * 64;
    const int s_base = sblk + wave * 16;
    const int s_glob = s_base + l15;

    const short* qrow = (const short*)Q + (size_t)(b * 2048 + s_glob) * 1024 + h * 64;
    s16x8 qf0 = *(const s16x8*)(qrow + q * 8);
    s16x8 qf1 = *(const s16x8*)(qrow + 32 + q * 8);

    float l_lane = 0.f;
    f32x4 o_acc[4] = {};

    const int srow = lane >> 3;              // 0..7
    const int gch  = (lane & 7) ^ srow;      // permuted global chunk
    const short*    kbase = (const short*)KV +
        (size_t)(b * 2048 + wave * 16 + srow) * 2048 + h * 64 + gch * 8;
    const _Float16* vbase = Vt +
        (size_t)(b * 1024 + h * 64 + wave * 16 + srow) * 2048 + gch * 8;
    const int key = l15 & 7;                 // frag-read swizzle key

    for (int t0 = 0; t0 < 2048; t0 += 64) {
        const bool needV = (t0 >= sblk);
        const short*    kg = kbase + (size_t)t0 * 2048;
        const _Float16* vg = vbase + t0;
        __syncthreads();
        async16(kg,                    &Ks[wave * 16][0]);
        async16(kg + (size_t)8 * 2048, &Ks[wave * 16 + 8][0]);
        if (needV) {
            async16((const short*)vg,                    (short*)&Vs[wave * 16][0]);
            async16((const short*)(vg + (size_t)8 * 2048), (short*)&Vs[wave * 16 + 8][0]);
        }
        __syncthreads();

#pragma unroll
        for (int sub = 0; sub < 4; sub++) {
            const int tb  = sub * 16;
            const int rel = t0 + tb - s_base;   // wave-uniform
            s16x8 kf0 = *(const s16x8*)&Ks[tb + l15][(q ^ key) * 8];
            s16x8 kf1 = *(const s16x8*)&Ks[tb + l15][((q + 4) ^ key) * 8];
            f32x4 st = {};
            st = __builtin_amdgcn_mfma_f32_16x16x32_bf16(kf0, qf0, st, 0, 0, 0);
            st = __builtin_amdgcn_mfma_f32_16x16x32_bf16(kf1, qf1, st, 0, 0, 0);
            float p[4];
#pragma unroll
            for (int r = 0; r < 4; r++) {
                float sc = st[r] * 0.125f;
                p[r] = __expf(fminf(sc, 60.f));
                l_lane += p[r];
            }
            if (rel >= 0) {
                h16x4 pf;
                if (rel == 0) {
#pragma unroll
                    for (int r = 0; r < 4; r++)
                        pf[r] = (q * 4 + r > l15) ? (_Float16)p[r] : (_Float16)0.f;
                } else {
#pragma unroll
                    for (int r = 0; r < 4; r++) pf[r] = (_Float16)p[r];
                }
#pragma unroll
                for (int dt = 0; dt < 4; dt++) {
                    // B[k=t=tb+q*4+j][n=d=dt*16+l15]; t-chunk 2*sub+(q>>1),
                    // offset (q&1)*4; chunk' = chunk ^ (d&7)
                    h16x4 vf = *(const h16x4*)&Vs[dt * 16 + l15]
                        [(((2 * sub + (q >> 1)) ^ key) * 8) + (q & 1) * 4];
                    o_acc[dt] = __builtin_amdgcn_mfma_f32_16x16x16f16(pf, vf, o_acc[dt], 0, 0, 0);
                }
            }
        }
    }

    float l = l_lane;
    l += __shfl_xor(l, 16, 64);
    l += __shfl_xor(l, 32, 64);
    float linv[4];
#pragma unroll
    for (int r = 0; r < 4; r++) linv[r] = 1.f / __shfl(l, q * 4 + r, 64);
#pragma unroll
    for (int dt = 0; dt < 4; dt++)
#pragma unroll
        for (int r = 0; r < 4; r++) {
            int s = s_base + q * 4 + r;
            int d = dt * 16 + l15;
            O[(size_t)(b * 2048 + s) * 1024 + h * 64 + d] =
                __float2bfloat16(o_acc[dt][r] * linv[r]);
        }
}

// ------------------------------- launcher ----------------------------------
extern "C" void kernel_launch(void* const* d_in, const int* in_sizes, int n_in,
                              void* d_out, int out_size, void* d_ws, size_t ws_size,
                              hipStream_t stream)
{
    const void* x     = d_in[0];
    const void* y     = d_in[1];
    const void* Wq    = d_in[2];
    const void* Wk    = d_in[3];
    const void* Wv    = d_in[4];
    const void* li1_w = d_in[5];
    const void* li1_b = d_in[6];
    const void* ln1_w = d_in[7];
    const void* ln1_b = d_in[8];
    const void* ln2_w = d_in[9];
    const void* ln2_b = d_in[10];
    const void* ln3_w = d_in[11];
    const void* ln3_b = d_in[12];
    const void* li2_w = d_in[13];
    const void* li2_b = d_in[14];
    const void* li3_w = d_in[15];
    const void* li3_b = d_in[16];

    char* w = (char*)d_ws;
    const size_t MB = 1u << 20;
    bf16* xn    = (bf16*)(w + 0 * MB);
    bf16* yn    = (bf16*)(w + 8 * MB);
    bf16* WqT   = (bf16*)(w + 16 * MB);
    bf16* WkT   = (bf16*)(w + 18 * MB);   // WkT+WvT contiguous = fused KV weights
    bf16* WvT   = (bf16*)(w + 20 * MB);
    bf16* li1T  = (bf16*)(w + 22 * MB);
    bf16* li2T  = (bf16*)(w + 24 * MB);
    bf16* li3T  = (bf16*)(w + 32 * MB);
    bf16* xout  = (bf16*)(w + 40 * MB);
    bf16* Qb    = (bf16*)(w + 48 * MB);
    bf16* KVb   = (bf16*)(w + 56 * MB);   // [4096][2048], 16MB
    _Float16* Vt = (_Float16*)(w + 72 * MB); // [2][1024][2048] f16, 8MB
    bf16* h2    = (bf16*)(w + 48 * MB);   // reuses Qb/KVb/Vt after attention
    bf16* xc    = (bf16*)(w + 80 * MB);   // canonical bf16 copy of x (residual)
    int*  flag  = (int*) (w + 88 * MB);
    bf16* li1bc = (bf16*)(w + 88 * MB + 4096);
    bf16* li2bc = (bf16*)(w + 88 * MB + 8192);
    bf16* li3bc = (bf16*)(w + 88 * MB + 24576);
    bf16* Ob    = yn;                     // reuse yn after KV projection
    bf16* hn    = xn;                     // reuse xn after Q projection

    // 0. dtype detection (deterministic per input -> graph-safe)
    detect_dtype<<<1, 256, 0, stream>>>((const short*)x, flag);

    // 1. biases (single launch)
    conv_bias3<<<24, 256, 0, stream>>>(li1_b, li2_b, li3_b, li1bc, li2bc, li3bc, flag);

    // 2. LayerNorms (LN1 also emits the canonical bf16 copy of x)
    ln_kernel<<<4096, 256, 0, stream>>>(x, ln1_w, ln1_b, xn, flag, 0, xc);
    ln_kernel<<<4096, 256, 0, stream>>>(y, ln2_w, ln2_b, yn, flag, 0, nullptr);

    // 3. weight re-layouts (LDS-tiled, coalesced)
    pack_qkv_tiled<<<dim3(2, 32, 16), 256, 0, stream>>>(Wq, WqT, flag);
    pack_qkv_tiled<<<dim3(2, 32, 16), 256, 0, stream>>>(Wk, WkT, flag);
    pack_qkv_tiled<<<dim3(2, 32, 16), 256, 0, stream>>>(Wv, WvT, flag);
    transpose_tiled<<<dim3(32, 32),  256, 0, stream>>>(li1_w, li1T, 1024, 1024, flag);
    transpose_tiled<<<dim3(128, 32), 256, 0, stream>>>(li2_w, li2T, 1024, 4096, flag);
    transpose_tiled<<<dim3(32, 128), 256, 0, stream>>>(li3_w, li3T, 4096, 1024, flag);

    // 4. projections: Q (N=1024) and fused KV (N=2048), then V -> Vt (f16)
    gemm_bt64<<<dim3(32, 16), 256, 0, stream>>>(xn, WqT, nullptr, nullptr, Qb, 4096, 1024, 1024, 0, flag, 0);
    gemm_bt64<<<dim3(32, 32), 256, 0, stream>>>(yn, WkT, nullptr, nullptr, KVb, 4096, 2048, 1024, 0, flag, 0);
    v_transpose<<<dim3(64, 32, 2), 256, 0, stream>>>(KVb, Vt);

    // 5. attention -> O [B,S,H*D]
    attn_kernel<<<dim3(32, 32), 256, 0, stream>>>(Qb, KVb, Vt, Ob);

    // 6. x_out = x + O @ li1_w + li1_b
    gemm_bt64<<<dim3(32, 16), 256, 0, stream>>>(Ob, li1T, li1bc, xc, xout, 4096, 1024, 1024, 0, flag, 0);

    // 7. hn = LN3(x_out)
    ln_kernel<<<4096, 256, 0, stream>>>(xout, ln3_w, ln3_b, hn, flag, 1, nullptr);

    // 8. h2 = gelu(hn @ li2_w + li2_b)
    gemm_bt128<<<dim3(32, 32), 256, 0, stream>>>(hn, li2T, li2bc, nullptr, h2, 4096, 4096, 1024, 1, flag, 0);

    // 9. out = x_out + h2 @ li3_w + li3_b   (dtype-matched store)
    gemm_bt64<<<dim3(32, 16), 256, 0, stream>>>(h2, li3T, li3bc, xout, d_out, 4096, 1024, 4096, 0, flag, 1);
}

// Round 9
// 478.736 us; speedup vs baseline: 1.4689x; 1.0498x over previous
//
#include <hip/hip_runtime.h>
#include <hip/hip_bf16.h>

// ---------------------------------------------------------------------------
// MultiHeadAttention block on MI355X (gfx950). Inputs float32 (device-detected,
// kept for robustness). Internal pipeline bf16 MFMA, fp32 accumulate.
// Round-9 changes (attention HBM replication):
//   * XCD-aware grid: attn grid = (bh, stile). dispatch id = stile*32+bh ->
//     id%8 = bh%8, so ALL s-blocks of one (b,h) land on ONE XCD; its L2
//     holds that head's K+V (512 KB << 4 MB). Round-8 FETCH=128MB was ~8x
//     cross-XCD replication of K/V (id%8 varied with stile).
//   * Q pre-scaled by 0.125 in the projection epilogue (ascale param);
//     per-score fmin clamp dropped -> 2 fewer VALU ops/score.
// Workspace (88MB + 32KB):
//   [0,8M) xn/hn  [8,16M) yn/O  [16,24M) WqT,WkT,WvT,li1T  [24,32M) li2T
//   [32,40M) li3T  [40,48M) xout  [48,56M) Qb  [56,72M) KVb  [72,80M) Vt
//   [48,80M) h2 (after attn)  [80,88M) xc  [88M) flag + biases
// ---------------------------------------------------------------------------

typedef __hip_bfloat16 bf16;
typedef __attribute__((ext_vector_type(8))) short  s16x8;
typedef __attribute__((ext_vector_type(4))) short  s16x4;
typedef __attribute__((ext_vector_type(4))) float  f32x4;
typedef __attribute__((ext_vector_type(4))) _Float16 h16x4;

__device__ __forceinline__ float bfbits2f(short s) {
    return __uint_as_float(((unsigned)(unsigned short)s) << 16);
}
__device__ __forceinline__ float load_in(const void* p, size_t i, int f32) {
    return f32 ? ((const float*)p)[i] : bfbits2f(((const short*)p)[i]);
}
// async global->LDS, 16B/lane; lds base wave-uniform, lane i -> base+16i
__device__ __forceinline__ void async16(const short* g, short* l) {
    __builtin_amdgcn_global_load_lds(
        (const __attribute__((address_space(1))) void*)g,
        (__attribute__((address_space(3))) void*)l, 16, 0, 0);
}

// ------------------------- dtype detection ---------------------------------
__global__ __launch_bounds__(256)
void detect_dtype(const short* __restrict__ x, int* __restrict__ flag)
{
    const int tid = threadIdx.x;
    int cnt = 0;
#pragma unroll
    for (int e = 0; e < 16; e++) {
        int idx = (tid * 16 + e) * 2;            // even shorts only
        int ex  = (x[idx] >> 7) & 0xFF;
        if (ex >= 113 && ex <= 142) cnt++;
    }
#pragma unroll
    for (int off = 1; off < 64; off <<= 1) cnt += __shfl_xor(cnt, off, 64);
    __shared__ int sh[4];
    if ((tid & 63) == 0) sh[tid >> 6] = cnt;
    __syncthreads();
    if (tid == 0) {
        int tot = sh[0] + sh[1] + sh[2] + sh[3];  // bf16: ~4096, f32: ~480
        flag[0] = (tot < 2458) ? 1 : 0;           // 1 == inputs are float32
    }
}

// --------------------- conversions / tiled transposes ----------------------
__global__ __launch_bounds__(256)
void conv_bias3(const void* b1, const void* b2, const void* b3,
                bf16* o1, bf16* o2, bf16* o3, const int* __restrict__ flag)
{
    const int f32 = flag[0];
    int i = blockIdx.x * 256 + threadIdx.x;      // 0..6143
    if (i < 1024)      o1[i]        = __float2bfloat16(load_in(b1, i, f32));
    else if (i < 5120) o2[i - 1024] = __float2bfloat16(load_in(b2, i - 1024, f32));
    else               o3[i - 5120] = __float2bfloat16(load_in(b3, i - 5120, f32));
}

// in [R,Cc] -> out [Cc,R], 32x32 LDS tiles, coalesced both sides
__global__ __launch_bounds__(256)
void transpose_tiled(const void* __restrict__ in, bf16* __restrict__ out,
                     int R, int Cc, const int* __restrict__ flag)
{
    __shared__ float tile[32][33];
    const int f32 = flag[0];
    const int tx = threadIdx.x & 31, ty = threadIdx.x >> 5;   // ty 0..7
    const int c0 = blockIdx.x * 32, r0 = blockIdx.y * 32;
#pragma unroll
    for (int i = 0; i < 4; i++)
        tile[ty + i * 8][tx] = load_in(in, (size_t)(r0 + ty + i * 8) * Cc + c0 + tx, f32);
    __syncthreads();
#pragma unroll
    for (int i = 0; i < 4; i++)
        out[(size_t)(c0 + ty + i * 8) * R + r0 + tx] = __float2bfloat16(tile[tx][ty + i * 8]);
}

// Wq [H][C=1024][D=64] -> WqT [H][D][C]  (per-head 1024x64 transpose)
__global__ __launch_bounds__(256)
void pack_qkv_tiled(const void* __restrict__ in, bf16* __restrict__ out,
                    const int* __restrict__ flag)
{
    __shared__ float tile[32][33];
    const int f32 = flag[0];
    const int tx = threadIdx.x & 31, ty = threadIdx.x >> 5;
    const int c0 = blockIdx.x * 32, r0 = blockIdx.y * 32;   // c: D, r: C
    const size_t base = (size_t)blockIdx.z * 1024 * 64;
#pragma unroll
    for (int i = 0; i < 4; i++)
        tile[ty + i * 8][tx] = load_in(in, base + (size_t)(r0 + ty + i * 8) * 64 + c0 + tx, f32);
    __syncthreads();
#pragma unroll
    for (int i = 0; i < 4; i++)
        out[base + (size_t)(c0 + ty + i * 8) * 1024 + r0 + tx] =
            __float2bfloat16(tile[tx][ty + i * 8]);
}

// V part of KVb [b][t][1024+hd] -> Vt [b][hd][t] as f16
__global__ __launch_bounds__(256)
void v_transpose(const bf16* __restrict__ KV, _Float16* __restrict__ Vt)
{
    __shared__ short tile[32][33];
    const int tx = threadIdx.x & 31, ty = threadIdx.x >> 5;
    const int t0 = blockIdx.x * 32, hd0 = blockIdx.y * 32, b = blockIdx.z;
#pragma unroll
    for (int i = 0; i < 4; i++)
        tile[ty + i * 8][tx] =
            ((const short*)KV)[(size_t)(b * 2048 + t0 + ty + i * 8) * 2048 + 1024 + hd0 + tx];
    __syncthreads();
#pragma unroll
    for (int i = 0; i < 4; i++)
        Vt[(size_t)(b * 1024 + hd0 + ty + i * 8) * 2048 + t0 + tx] =
            (_Float16)bfbits2f(tile[tx][ty + i * 8]);
}

// ------------------------------- LayerNorm ---------------------------------
__global__ __launch_bounds__(256)
void ln_kernel(const void* __restrict__ x, const void* __restrict__ w,
               const void* __restrict__ bv, bf16* __restrict__ out,
               const int* __restrict__ flag, int x_is_bf16,
               bf16* __restrict__ copy_out)
{
    const int f32  = flag[0];
    const int xf32 = x_is_bf16 ? 0 : f32;
    const int row  = blockIdx.x;
    const int tid  = threadIdx.x;
    const int lane = tid & 63;
    const int wave = tid >> 6;
    const size_t base = (size_t)row * 1024 + tid * 4;

    float v[4];
    float sum = 0.f, ss = 0.f;
#pragma unroll
    for (int e = 0; e < 4; e++) {
        v[e] = load_in(x, base + e, xf32);
        sum += v[e]; ss += v[e] * v[e];
    }
    if (copy_out) {
        s16x4 c;
#pragma unroll
        for (int e = 0; e < 4; e++) {
            __hip_bfloat16 hb = __float2bfloat16(v[e]);
            c[e] = *(short*)&hb;
        }
        *(s16x4*)((short*)copy_out + base) = c;
    }
#pragma unroll
    for (int off = 1; off < 64; off <<= 1) {
        sum += __shfl_xor(sum, off, 64);
        ss  += __shfl_xor(ss,  off, 64);
    }
    __shared__ float sh1[4], sh2[4];
    if (lane == 0) { sh1[wave] = sum; sh2[wave] = ss; }
    __syncthreads();
    float t1 = sh1[0] + sh1[1] + sh1[2] + sh1[3];
    float t2 = sh2[0] + sh2[1] + sh2[2] + sh2[3];
    float mu   = t1 * (1.f / 1024.f);
    float var  = t2 * (1.f / 1024.f) - mu * mu;
    float rstd = rsqrtf(var + 1e-5f);

#pragma unroll
    for (int e = 0; e < 4; e++) {
        float ov = (v[e] - mu) * rstd * load_in(w, tid * 4 + e, f32)
                 + load_in(bv, tid * 4 + e, f32);
        out[base + e] = __float2bfloat16(ov);
    }
}

// ------------------- GEMM 128x64x64, swizzled staging ----------------------
// ascale: multiplies the accumulator before bias (used to fold the 1/sqrt(D)
// attention scale into the Q projection).
__global__ __launch_bounds__(256)
void gemm_bt64(const bf16* __restrict__ A, const bf16* __restrict__ Bt,
               const bf16* __restrict__ bias, const bf16* __restrict__ res,
               void* __restrict__ C, int M, int N, int K, int act,
               const int* __restrict__ dflag, int final_out, float ascale)
{
    __shared__ alignas(16) short As[128][64];
    __shared__ alignas(16) short Bs[64][64];

    const int f32out = final_out ? dflag[0] : 0;
    const int tid  = threadIdx.x;
    const int lane = tid & 63;
    const int wave = tid >> 6;
    const int q    = lane >> 4;
    const int l15  = lane & 15;
    const int wm   = (wave >> 1) * 64;
    const int wn   = (wave & 1) * 32;
    const int bm   = blockIdx.x * 128;
    const int bn   = blockIdx.y * 64;

    const int srow   = lane >> 3;              // 0..7
    const int gchunk = (lane & 7) ^ srow;      // permuted global chunk
    const short* Ab = (const short*)A  + (size_t)(bm + wave * 32 + srow) * K + gchunk * 8;
    const short* Bb = (const short*)Bt + (size_t)(bn + wave * 16 + srow) * K + gchunk * 8;
    const int csw = l15 & 7;

    f32x4 acc[4][2] = {};

    for (int k0 = 0; k0 < K; k0 += 64) {
        __syncthreads();
        async16(Ab + k0,                  &As[wave * 32][0]);
        async16(Ab + k0 + (size_t)8  * K, &As[wave * 32 + 8][0]);
        async16(Ab + k0 + (size_t)16 * K, &As[wave * 32 + 16][0]);
        async16(Ab + k0 + (size_t)24 * K, &As[wave * 32 + 24][0]);
        async16(Bb + k0,                  &Bs[wave * 16][0]);
        async16(Bb + k0 + (size_t)8  * K, &Bs[wave * 16 + 8][0]);
        __syncthreads();

        s16x8 af[4][2], bfr[2][2];
#pragma unroll
        for (int i = 0; i < 4; i++)
#pragma unroll
            for (int kk = 0; kk < 2; kk++)
                af[i][kk] = *(const s16x8*)&As[wm + i * 16 + l15][((kk * 4 + q) ^ csw) * 8];
#pragma unroll
        for (int j = 0; j < 2; j++)
#pragma unroll
            for (int kk = 0; kk < 2; kk++)
                bfr[j][kk] = *(const s16x8*)&Bs[wn + j * 16 + l15][((kk * 4 + q) ^ csw) * 8];
#pragma unroll
        for (int i = 0; i < 4; i++)
#pragma unroll
            for (int j = 0; j < 2; j++) {
                acc[i][j] = __builtin_amdgcn_mfma_f32_16x16x32_bf16(af[i][0], bfr[j][0], acc[i][j], 0, 0, 0);
                acc[i][j] = __builtin_amdgcn_mfma_f32_16x16x32_bf16(af[i][1], bfr[j][1], acc[i][j], 0, 0, 0);
            }
    }

#pragma unroll
    for (int i = 0; i < 4; i++) {
#pragma unroll
        for (int j = 0; j < 2; j++) {
            int n = bn + wn + j * 16 + l15;
            float bvv = bias ? __bfloat162float(bias[n]) : 0.f;
#pragma unroll
            for (int r = 0; r < 4; r++) {
                int m = bm + wm + i * 16 + q * 4 + r;
                float v = acc[i][j][r] * ascale + bvv;
                if (act) v = 0.5f * v * (1.f + erff(v * 0.70710678118f));
                if (res) v += __bfloat162float(res[(size_t)m * N + n]);
                size_t idx = (size_t)m * N + n;
                if (f32out) ((float*)C)[idx] = v;
                else        ((bf16*)C)[idx]  = __float2bfloat16(v);
            }
        }
    }
}

// ------------------- GEMM 128x128x64, swizzled staging (li2) ---------------
__global__ __launch_bounds__(256)
void gemm_bt128(const bf16* __restrict__ A, const bf16* __restrict__ Bt,
                const bf16* __restrict__ bias, const bf16* __restrict__ res,
                void* __restrict__ C, int M, int N, int K, int act,
                const int* __restrict__ dflag, int final_out)
{
    __shared__ alignas(16) short As[128][64];
    __shared__ alignas(16) short Bs[128][64];

    const int f32out = final_out ? dflag[0] : 0;
    const int tid  = threadIdx.x;
    const int lane = tid & 63;
    const int wave = tid >> 6;
    const int q    = lane >> 4;
    const int l15  = lane & 15;
    const int wm   = (wave >> 1) * 64;
    const int wn   = (wave & 1) * 64;
    const int bm   = blockIdx.x * 128;
    const int bn   = blockIdx.y * 128;

    const int srow   = lane >> 3;
    const int gchunk = (lane & 7) ^ srow;
    const short* Ab = (const short*)A  + (size_t)(bm + wave * 32 + srow) * K + gchunk * 8;
    const short* Bb = (const short*)Bt + (size_t)(bn + wave * 32 + srow) * K + gchunk * 8;
    const int csw = l15 & 7;

    f32x4 acc[4][4] = {};

    for (int k0 = 0; k0 < K; k0 += 64) {
        __syncthreads();
#pragma unroll
        for (int r8 = 0; r8 < 4; r8++) {
            async16(Ab + k0 + (size_t)(r8 * 8) * K, &As[wave * 32 + r8 * 8][0]);
            async16(Bb + k0 + (size_t)(r8 * 8) * K, &Bs[wave * 32 + r8 * 8][0]);
        }
        __syncthreads();

#pragma unroll
        for (int kk = 0; kk < 2; kk++) {
            s16x8 af[4], bfr[4];
#pragma unroll
            for (int i = 0; i < 4; i++) af[i]  = *(const s16x8*)&As[wm + i * 16 + l15][((kk * 4 + q) ^ csw) * 8];
#pragma unroll
            for (int j = 0; j < 4; j++) bfr[j] = *(const s16x8*)&Bs[wn + j * 16 + l15][((kk * 4 + q) ^ csw) * 8];
#pragma unroll
            for (int i = 0; i < 4; i++)
#pragma unroll
                for (int j = 0; j < 4; j++)
                    acc[i][j] = __builtin_amdgcn_mfma_f32_16x16x32_bf16(af[i], bfr[j], acc[i][j], 0, 0, 0);
        }
    }

#pragma unroll
    for (int i = 0; i < 4; i++) {
#pragma unroll
        for (int j = 0; j < 4; j++) {
            int n = bn + wn + j * 16 + l15;
            float bvv = bias ? __bfloat162float(bias[n]) : 0.f;
#pragma unroll
            for (int r = 0; r < 4; r++) {
                int m = bm + wm + i * 16 + q * 4 + r;
                float v = acc[i][j][r] + bvv;
                if (act) v = 0.5f * v * (1.f + erff(v * 0.70710678118f));
                if (res) v += __bfloat162float(res[(size_t)m * N + n]);
                size_t idx = (size_t)m * N + n;
                if (f32out) ((float*)C)[idx] = v;
                else        ((bf16*)C)[idx]  = __float2bfloat16(v);
            }
        }
    }
}

// ------------------------------ Attention ----------------------------------
// grid (B*H, S/64)  <-- XCD-aware: dispatch id = stile*32+bh, id%8 = bh%8,
// so all s-blocks of one (b,h) share an XCD; K+V (512 KB) stay L2-resident.
// 4 waves; wave = 16 q-rows, loops all t in 64-tiles.
// K from fused KVb (col h*64); V from pre-transposed Vt[b][h*64+d][t] (f16).
// Both staged via global_load_lds w16, unpadded [64][64], chunk-permuted.
// Q pre-scaled by 0.125 in its projection. Post-softmax mask => l pure sum.
__global__ __launch_bounds__(256)
void attn_kernel(const bf16* __restrict__ Q, const bf16* __restrict__ KV,
                 const _Float16* __restrict__ Vt, bf16* __restrict__ O)
{
    __shared__ alignas(16) short    Ks[64][64];   // [t][d'], chunk-swizzled
    __shared__ alignas(16) _Float16 Vs[64][64];   // [d][t'], chunk-swizzled

    const int tid  = threadIdx.x;
    const int lane = tid & 63;
    const int wave = tid >> 6;
    const int q    = lane >> 4;
    const int l15  = lane & 15;
    const int bh   = blockIdx.x;                  // XCD key
    const int b    = bh >> 4, h = bh & 15;
    const int sblk   = blockIdx.y * 64;
    const int s_base = sblk + wave * 16;
    const int s_glob = s_base + l15;

    const short* qrow = (const short*)Q + (size_t)(b * 2048 + s_glob) * 1024 + h * 64;
    s16x8 qf0 = *(const s16x8*)(qrow + q * 8);
    s16x8 qf1 = *(const s16x8*)(qrow + 32 + q * 8);

    float l_lane = 0.f;
    f32x4 o_acc[4] = {};

    const int srow = lane >> 3;              // 0..7
    const int gch  = (lane & 7) ^ srow;      // permuted global chunk
    const short*    kbase = (const short*)KV +
        (size_t)(b * 2048 + wave * 16 + srow) * 2048 + h * 64 + gch * 8;
    const _Float16* vbase = Vt +
        (size_t)(b * 1024 + h * 64 + wave * 16 + srow) * 2048 + gch * 8;
    const int key = l15 & 7;                 // frag-read swizzle key

    for (int t0 = 0; t0 < 2048; t0 += 64) {
        const bool needV = (t0 >= sblk);
        const short*    kg = kbase + (size_t)t0 * 2048;
        const _Float16* vg = vbase + t0;
        __syncthreads();
        async16(kg,                    &Ks[wave * 16][0]);
        async16(kg + (size_t)8 * 2048, &Ks[wave * 16 + 8][0]);
        if (needV) {
            async16((const short*)vg,                      (short*)&Vs[wave * 16][0]);
            async16((const short*)(vg + (size_t)8 * 2048), (short*)&Vs[wave * 16 + 8][0]);
        }
        __syncthreads();

#pragma unroll
        for (int sub = 0; sub < 4; sub++) {
            const int tb  = sub * 16;
            const int rel = t0 + tb - s_base;   // wave-uniform
            s16x8 kf0 = *(const s16x8*)&Ks[tb + l15][(q ^ key) * 8];
            s16x8 kf1 = *(const s16x8*)&Ks[tb + l15][((q + 4) ^ key) * 8];
            f32x4 st = {};
            st = __builtin_amdgcn_mfma_f32_16x16x32_bf16(kf0, qf0, st, 0, 0, 0);
            st = __builtin_amdgcn_mfma_f32_16x16x32_bf16(kf1, qf1, st, 0, 0, 0);
            // scores already scaled (Q pre-scaled by 0.125); bounded -> no clamp
            float p[4];
#pragma unroll
            for (int r = 0; r < 4; r++) {
                p[r] = __expf(st[r]);
                l_lane += p[r];
            }
            if (rel >= 0) {
                h16x4 pf;
                if (rel == 0) {
#pragma unroll
                    for (int r = 0; r < 4; r++)
                        pf[r] = (q * 4 + r > l15) ? (_Float16)p[r] : (_Float16)0.f;
                } else {
#pragma unroll
                    for (int r = 0; r < 4; r++) pf[r] = (_Float16)p[r];
                }
#pragma unroll
                for (int dt = 0; dt < 4; dt++) {
                    h16x4 vf = *(const h16x4*)&Vs[dt * 16 + l15]
                        [(((2 * sub + (q >> 1)) ^ key) * 8) + (q & 1) * 4];
                    o_acc[dt] = __builtin_amdgcn_mfma_f32_16x16x16f16(pf, vf, o_acc[dt], 0, 0, 0);
                }
            }
        }
    }

    float l = l_lane;
    l += __shfl_xor(l, 16, 64);
    l += __shfl_xor(l, 32, 64);
    float linv[4];
#pragma unroll
    for (int r = 0; r < 4; r++) linv[r] = 1.f / __shfl(l, q * 4 + r, 64);
#pragma unroll
    for (int dt = 0; dt < 4; dt++)
#pragma unroll
        for (int r = 0; r < 4; r++) {
            int s = s_base + q * 4 + r;
            int d = dt * 16 + l15;
            O[(size_t)(b * 2048 + s) * 1024 + h * 64 + d] =
                __float2bfloat16(o_acc[dt][r] * linv[r]);
        }
}

// ------------------------------- launcher ----------------------------------
extern "C" void kernel_launch(void* const* d_in, const int* in_sizes, int n_in,
                              void* d_out, int out_size, void* d_ws, size_t ws_size,
                              hipStream_t stream)
{
    const void* x     = d_in[0];
    const void* y     = d_in[1];
    const void* Wq    = d_in[2];
    const void* Wk    = d_in[3];
    const void* Wv    = d_in[4];
    const void* li1_w = d_in[5];
    const void* li1_b = d_in[6];
    const void* ln1_w = d_in[7];
    const void* ln1_b = d_in[8];
    const void* ln2_w = d_in[9];
    const void* ln2_b = d_in[10];
    const void* ln3_w = d_in[11];
    const void* ln3_b = d_in[12];
    const void* li2_w = d_in[13];
    const void* li2_b = d_in[14];
    const void* li3_w = d_in[15];
    const void* li3_b = d_in[16];

    char* w = (char*)d_ws;
    const size_t MB = 1u << 20;
    bf16* xn    = (bf16*)(w + 0 * MB);
    bf16* yn    = (bf16*)(w + 8 * MB);
    bf16* WqT   = (bf16*)(w + 16 * MB);
    bf16* WkT   = (bf16*)(w + 18 * MB);   // WkT+WvT contiguous = fused KV weights
    bf16* WvT   = (bf16*)(w + 20 * MB);
    bf16* li1T  = (bf16*)(w + 22 * MB);
    bf16* li2T  = (bf16*)(w + 24 * MB);
    bf16* li3T  = (bf16*)(w + 32 * MB);
    bf16* xout  = (bf16*)(w + 40 * MB);
    bf16* Qb    = (bf16*)(w + 48 * MB);
    bf16* KVb   = (bf16*)(w + 56 * MB);   // [4096][2048], 16MB
    _Float16* Vt = (_Float16*)(w + 72 * MB); // [2][1024][2048] f16, 8MB
    bf16* h2    = (bf16*)(w + 48 * MB);   // reuses Qb/KVb/Vt after attention
    bf16* xc    = (bf16*)(w + 80 * MB);   // canonical bf16 copy of x (residual)
    int*  flag  = (int*) (w + 88 * MB);
    bf16* li1bc = (bf16*)(w + 88 * MB + 4096);
    bf16* li2bc = (bf16*)(w + 88 * MB + 8192);
    bf16* li3bc = (bf16*)(w + 88 * MB + 24576);
    bf16* Ob    = yn;                     // reuse yn after KV projection
    bf16* hn    = xn;                     // reuse xn after Q projection

    // 0. dtype detection (deterministic per input -> graph-safe)
    detect_dtype<<<1, 256, 0, stream>>>((const short*)x, flag);

    // 1. biases (single launch)
    conv_bias3<<<24, 256, 0, stream>>>(li1_b, li2_b, li3_b, li1bc, li2bc, li3bc, flag);

    // 2. LayerNorms (LN1 also emits the canonical bf16 copy of x)
    ln_kernel<<<4096, 256, 0, stream>>>(x, ln1_w, ln1_b, xn, flag, 0, xc);
    ln_kernel<<<4096, 256, 0, stream>>>(y, ln2_w, ln2_b, yn, flag, 0, nullptr);

    // 3. weight re-layouts (LDS-tiled, coalesced)
    pack_qkv_tiled<<<dim3(2, 32, 16), 256, 0, stream>>>(Wq, WqT, flag);
    pack_qkv_tiled<<<dim3(2, 32, 16), 256, 0, stream>>>(Wk, WkT, flag);
    pack_qkv_tiled<<<dim3(2, 32, 16), 256, 0, stream>>>(Wv, WvT, flag);
    transpose_tiled<<<dim3(32, 32),  256, 0, stream>>>(li1_w, li1T, 1024, 1024, flag);
    transpose_tiled<<<dim3(128, 32), 256, 0, stream>>>(li2_w, li2T, 1024, 4096, flag);
    transpose_tiled<<<dim3(32, 128), 256, 0, stream>>>(li3_w, li3T, 4096, 1024, flag);

    // 4. projections: Q (pre-scaled by 1/8) and fused KV, then V -> Vt (f16)
    gemm_bt64<<<dim3(32, 16), 256, 0, stream>>>(xn, WqT, nullptr, nullptr, Qb, 4096, 1024, 1024, 0, flag, 0, 0.125f);
    gemm_bt64<<<dim3(32, 32), 256, 0, stream>>>(yn, WkT, nullptr, nullptr, KVb, 4096, 2048, 1024, 0, flag, 0, 1.0f);
    v_transpose<<<dim3(64, 32, 2), 256, 0, stream>>>(KVb, Vt);

    // 5. attention -> O [B,S,H*D]   (grid x=bh for XCD locality)
    attn_kernel<<<dim3(32, 32), 256, 0, stream>>>(Qb, KVb, Vt, Ob);

    // 6. x_out = x + O @ li1_w + li1_b
    gemm_bt64<<<dim3(32, 16), 256, 0, stream>>>(Ob, li1T, li1bc, xc, xout, 4096, 1024, 1024, 0, flag, 0, 1.0f);

    // 7. hn = LN3(x_out)
    ln_kernel<<<4096, 256, 0, stream>>>(xout, ln3_w, ln3_b, hn, flag, 1, nullptr);

    // 8. h2 = gelu(hn @ li2_w + li2_b)
    gemm_bt128<<<dim3(32, 32), 256, 0, stream>>>(hn, li2T, li2bc, nullptr, h2, 4096, 4096, 1024, 1, flag, 0);

    // 9. out = x_out + h2 @ li3_w + li3_b   (dtype-matched store)
    gemm_bt64<<<dim3(32, 16), 256, 0, stream>>>(h2, li3T, li3bc, xout, d_out, 4096, 1024, 4096, 0, flag, 1, 1.0f);
}

// Round 10
// 447.845 us; speedup vs baseline: 1.5702x; 1.0690x over previous
//
#include <hip/hip_runtime.h>
#include <hip/hip_bf16.h>

// ---------------------------------------------------------------------------
// MultiHeadAttention block on MI355X (gfx950). Inputs float32 (device-detected,
// kept for robustness). Internal pipeline bf16 MFMA, fp32 accumulate.
// Round-10 changes:
//   * Fast tanh-form GELU (exp+rcp, ~12 VALU) replaces erff (~25-30 VALU):
//     li2's epilogue VALU (64 erff/thread) cost as much as its whole K-loop
//     (VALUBusy 42% vs MfmaUtil 18%). |err|<1e-3, absmax margin 0.03->0.1025.
//   * gemm_bt64 templated KU: KU=2 stages two 64-wide K-slabs per barrier
//     pair (separate LDS buffers, IDENTICAL verified swizzle) -> 32 MFMA
//     per barrier. li3 (K=4096): 64 -> 32 barrier pairs. Q/li1/li3 use KU=2
//     (grid-limited 2 blocks/CU; 48KB LDS still allows 3); KV keeps KU=1
//     (grid 4/CU > LDS 3/CU at 48KB).
// Workspace (88MB + 32KB):
//   [0,8M) xn/hn  [8,16M) yn/O  [16,24M) WqT,WkT,WvT,li1T  [24,32M) li2T
//   [32,40M) li3T  [40,48M) xout  [48,56M) Qb  [56,72M) KVb  [72,80M) Vt
//   [48,80M) h2 (after attn)  [80,88M) xc  [88M) flag + biases
// ---------------------------------------------------------------------------

typedef __hip_bfloat16 bf16;
typedef __attribute__((ext_vector_type(8))) short  s16x8;
typedef __attribute__((ext_vector_type(4))) short  s16x4;
typedef __attribute__((ext_vector_type(4))) float  f32x4;
typedef __attribute__((ext_vector_type(4))) _Float16 h16x4;

__device__ __forceinline__ float bfbits2f(short s) {
    return __uint_as_float(((unsigned)(unsigned short)s) << 16);
}
__device__ __forceinline__ float load_in(const void* p, size_t i, int f32) {
    return f32 ? ((const float*)p)[i] : bfbits2f(((const short*)p)[i]);
}
// async global->LDS, 16B/lane; lds base wave-uniform, lane i -> base+16i
__device__ __forceinline__ void async16(const short* g, short* l) {
    __builtin_amdgcn_global_load_lds(
        (const __attribute__((address_space(1))) void*)g,
        (__attribute__((address_space(3))) void*)l, 16, 0, 0);
}
// tanh-form GELU: 0.5x(1+tanh(sqrt(2/pi)(x+0.044715x^3))), |err|<1e-3 vs erf
__device__ __forceinline__ float gelu_fast(float x) {
    float x2 = x * x;
    float z  = x * (0.7978845608f + 0.0356774081f * x2);
    z = fminf(z, 15.f);                      // exp guard (gelu(x)->x there)
    float e  = __expf(2.f * z);
    float t  = (e - 1.f) * __builtin_amdgcn_rcpf(e + 1.f);
    return 0.5f * x * (1.f + t);
}

// ------------------------- dtype detection ---------------------------------
__global__ __launch_bounds__(256)
void detect_dtype(const short* __restrict__ x, int* __restrict__ flag)
{
    const int tid = threadIdx.x;
    int cnt = 0;
#pragma unroll
    for (int e = 0; e < 16; e++) {
        int idx = (tid * 16 + e) * 2;            // even shorts only
        int ex  = (x[idx] >> 7) & 0xFF;
        if (ex >= 113 && ex <= 142) cnt++;
    }
#pragma unroll
    for (int off = 1; off < 64; off <<= 1) cnt += __shfl_xor(cnt, off, 64);
    __shared__ int sh[4];
    if ((tid & 63) == 0) sh[tid >> 6] = cnt;
    __syncthreads();
    if (tid == 0) {
        int tot = sh[0] + sh[1] + sh[2] + sh[3];  // bf16: ~4096, f32: ~480
        flag[0] = (tot < 2458) ? 1 : 0;           // 1 == inputs are float32
    }
}

// --------------------- conversions / tiled transposes ----------------------
__global__ __launch_bounds__(256)
void conv_bias3(const void* b1, const void* b2, const void* b3,
                bf16* o1, bf16* o2, bf16* o3, const int* __restrict__ flag)
{
    const int f32 = flag[0];
    int i = blockIdx.x * 256 + threadIdx.x;      // 0..6143
    if (i < 1024)      o1[i]        = __float2bfloat16(load_in(b1, i, f32));
    else if (i < 5120) o2[i - 1024] = __float2bfloat16(load_in(b2, i - 1024, f32));
    else               o3[i - 5120] = __float2bfloat16(load_in(b3, i - 5120, f32));
}

// in [R,Cc] -> out [Cc,R], 32x32 LDS tiles, coalesced both sides
__global__ __launch_bounds__(256)
void transpose_tiled(const void* __restrict__ in, bf16* __restrict__ out,
                     int R, int Cc, const int* __restrict__ flag)
{
    __shared__ float tile[32][33];
    const int f32 = flag[0];
    const int tx = threadIdx.x & 31, ty = threadIdx.x >> 5;   // ty 0..7
    const int c0 = blockIdx.x * 32, r0 = blockIdx.y * 32;
#pragma unroll
    for (int i = 0; i < 4; i++)
        tile[ty + i * 8][tx] = load_in(in, (size_t)(r0 + ty + i * 8) * Cc + c0 + tx, f32);
    __syncthreads();
#pragma unroll
    for (int i = 0; i < 4; i++)
        out[(size_t)(c0 + ty + i * 8) * R + r0 + tx] = __float2bfloat16(tile[tx][ty + i * 8]);
}

// Wq [H][C=1024][D=64] -> WqT [H][D][C]  (per-head 1024x64 transpose)
__global__ __launch_bounds__(256)
void pack_qkv_tiled(const void* __restrict__ in, bf16* __restrict__ out,
                    const int* __restrict__ flag)
{
    __shared__ float tile[32][33];
    const int f32 = flag[0];
    const int tx = threadIdx.x & 31, ty = threadIdx.x >> 5;
    const int c0 = blockIdx.x * 32, r0 = blockIdx.y * 32;   // c: D, r: C
    const size_t base = (size_t)blockIdx.z * 1024 * 64;
#pragma unroll
    for (int i = 0; i < 4; i++)
        tile[ty + i * 8][tx] = load_in(in, base + (size_t)(r0 + ty + i * 8) * 64 + c0 + tx, f32);
    __syncthreads();
#pragma unroll
    for (int i = 0; i < 4; i++)
        out[base + (size_t)(c0 + ty + i * 8) * 1024 + r0 + tx] =
            __float2bfloat16(tile[tx][ty + i * 8]);
}

// V part of KVb [b][t][1024+hd] -> Vt [b][hd][t] as f16
__global__ __launch_bounds__(256)
void v_transpose(const bf16* __restrict__ KV, _Float16* __restrict__ Vt)
{
    __shared__ short tile[32][33];
    const int tx = threadIdx.x & 31, ty = threadIdx.x >> 5;
    const int t0 = blockIdx.x * 32, hd0 = blockIdx.y * 32, b = blockIdx.z;
#pragma unroll
    for (int i = 0; i < 4; i++)
        tile[ty + i * 8][tx] =
            ((const short*)KV)[(size_t)(b * 2048 + t0 + ty + i * 8) * 2048 + 1024 + hd0 + tx];
    __syncthreads();
#pragma unroll
    for (int i = 0; i < 4; i++)
        Vt[(size_t)(b * 1024 + hd0 + ty + i * 8) * 2048 + t0 + tx] =
            (_Float16)bfbits2f(tile[tx][ty + i * 8]);
}

// ------------------------------- LayerNorm ---------------------------------
__global__ __launch_bounds__(256)
void ln_kernel(const void* __restrict__ x, const void* __restrict__ w,
               const void* __restrict__ bv, bf16* __restrict__ out,
               const int* __restrict__ flag, int x_is_bf16,
               bf16* __restrict__ copy_out)
{
    const int f32  = flag[0];
    const int xf32 = x_is_bf16 ? 0 : f32;
    const int row  = blockIdx.x;
    const int tid  = threadIdx.x;
    const int lane = tid & 63;
    const int wave = tid >> 6;
    const size_t base = (size_t)row * 1024 + tid * 4;

    float v[4];
    float sum = 0.f, ss = 0.f;
#pragma unroll
    for (int e = 0; e < 4; e++) {
        v[e] = load_in(x, base + e, xf32);
        sum += v[e]; ss += v[e] * v[e];
    }
    if (copy_out) {
        s16x4 c;
#pragma unroll
        for (int e = 0; e < 4; e++) {
            __hip_bfloat16 hb = __float2bfloat16(v[e]);
            c[e] = *(short*)&hb;
        }
        *(s16x4*)((short*)copy_out + base) = c;
    }
#pragma unroll
    for (int off = 1; off < 64; off <<= 1) {
        sum += __shfl_xor(sum, off, 64);
        ss  += __shfl_xor(ss,  off, 64);
    }
    __shared__ float sh1[4], sh2[4];
    if (lane == 0) { sh1[wave] = sum; sh2[wave] = ss; }
    __syncthreads();
    float t1 = sh1[0] + sh1[1] + sh1[2] + sh1[3];
    float t2 = sh2[0] + sh2[1] + sh2[2] + sh2[3];
    float mu   = t1 * (1.f / 1024.f);
    float var  = t2 * (1.f / 1024.f) - mu * mu;
    float rstd = rsqrtf(var + 1e-5f);

#pragma unroll
    for (int e = 0; e < 4; e++) {
        float ov = (v[e] - mu) * rstd * load_in(w, tid * 4 + e, f32)
                 + load_in(bv, tid * 4 + e, f32);
        out[base + e] = __float2bfloat16(ov);
    }
}

// ------------------- GEMM 128x64x(64*KU), swizzled staging -----------------
// KU=2: two 64-wide K-slabs staged per barrier pair (separate LDS buffers,
// identical swizzle) -> 32 MFMA/wave/barrier. ascale folds 1/sqrt(D) into Q.
template<int KU>
__global__ __launch_bounds__(256)
void gemm_bt64(const bf16* __restrict__ A, const bf16* __restrict__ Bt,
               const bf16* __restrict__ bias, const bf16* __restrict__ res,
               void* __restrict__ C, int M, int N, int K, int act,
               const int* __restrict__ dflag, int final_out, float ascale)
{
    __shared__ alignas(16) short As[KU][128][64];
    __shared__ alignas(16) short Bs[KU][64][64];

    const int f32out = final_out ? dflag[0] : 0;
    const int tid  = threadIdx.x;
    const int lane = tid & 63;
    const int wave = tid >> 6;
    const int q    = lane >> 4;
    const int l15  = lane & 15;
    const int wm   = (wave >> 1) * 64;
    const int wn   = (wave & 1) * 32;
    const int bm   = blockIdx.x * 128;
    const int bn   = blockIdx.y * 64;

    const int srow   = lane >> 3;              // 0..7
    const int gchunk = (lane & 7) ^ srow;      // permuted global chunk
    const short* Ab = (const short*)A  + (size_t)(bm + wave * 32 + srow) * K + gchunk * 8;
    const short* Bb = (const short*)Bt + (size_t)(bn + wave * 16 + srow) * K + gchunk * 8;
    const int csw = l15 & 7;

    f32x4 acc[4][2] = {};

    for (int k0 = 0; k0 < K; k0 += 64 * KU) {
        __syncthreads();
#pragma unroll
        for (int u = 0; u < KU; u++) {
            const int ko = k0 + u * 64;
            async16(Ab + ko,                  &As[u][wave * 32][0]);
            async16(Ab + ko + (size_t)8  * K, &As[u][wave * 32 + 8][0]);
            async16(Ab + ko + (size_t)16 * K, &As[u][wave * 32 + 16][0]);
            async16(Ab + ko + (size_t)24 * K, &As[u][wave * 32 + 24][0]);
            async16(Bb + ko,                  &Bs[u][wave * 16][0]);
            async16(Bb + ko + (size_t)8  * K, &Bs[u][wave * 16 + 8][0]);
        }
        __syncthreads();

#pragma unroll
        for (int u = 0; u < KU; u++) {
            s16x8 af[4][2], bfr[2][2];
#pragma unroll
            for (int i = 0; i < 4; i++)
#pragma unroll
                for (int kk = 0; kk < 2; kk++)
                    af[i][kk] = *(const s16x8*)&As[u][wm + i * 16 + l15][((kk * 4 + q) ^ csw) * 8];
#pragma unroll
            for (int j = 0; j < 2; j++)
#pragma unroll
                for (int kk = 0; kk < 2; kk++)
                    bfr[j][kk] = *(const s16x8*)&Bs[u][wn + j * 16 + l15][((kk * 4 + q) ^ csw) * 8];
#pragma unroll
            for (int i = 0; i < 4; i++)
#pragma unroll
                for (int j = 0; j < 2; j++) {
                    acc[i][j] = __builtin_amdgcn_mfma_f32_16x16x32_bf16(af[i][0], bfr[j][0], acc[i][j], 0, 0, 0);
                    acc[i][j] = __builtin_amdgcn_mfma_f32_16x16x32_bf16(af[i][1], bfr[j][1], acc[i][j], 0, 0, 0);
                }
        }
    }

#pragma unroll
    for (int i = 0; i < 4; i++) {
#pragma unroll
        for (int j = 0; j < 2; j++) {
            int n = bn + wn + j * 16 + l15;
            float bvv = bias ? __bfloat162float(bias[n]) : 0.f;
#pragma unroll
            for (int r = 0; r < 4; r++) {
                int m = bm + wm + i * 16 + q * 4 + r;
                float v = acc[i][j][r] * ascale + bvv;
                if (act) v = gelu_fast(v);
                if (res) v += __bfloat162float(res[(size_t)m * N + n]);
                size_t idx = (size_t)m * N + n;
                if (f32out) ((float*)C)[idx] = v;
                else        ((bf16*)C)[idx]  = __float2bfloat16(v);
            }
        }
    }
}

// ------------------- GEMM 128x128x64, swizzled staging (li2) ---------------
__global__ __launch_bounds__(256)
void gemm_bt128(const bf16* __restrict__ A, const bf16* __restrict__ Bt,
                const bf16* __restrict__ bias, const bf16* __restrict__ res,
                void* __restrict__ C, int M, int N, int K, int act,
                const int* __restrict__ dflag, int final_out)
{
    __shared__ alignas(16) short As[128][64];
    __shared__ alignas(16) short Bs[128][64];

    const int f32out = final_out ? dflag[0] : 0;
    const int tid  = threadIdx.x;
    const int lane = tid & 63;
    const int wave = tid >> 6;
    const int q    = lane >> 4;
    const int l15  = lane & 15;
    const int wm   = (wave >> 1) * 64;
    const int wn   = (wave & 1) * 64;
    const int bm   = blockIdx.x * 128;
    const int bn   = blockIdx.y * 128;

    const int srow   = lane >> 3;
    const int gchunk = (lane & 7) ^ srow;
    const short* Ab = (const short*)A  + (size_t)(bm + wave * 32 + srow) * K + gchunk * 8;
    const short* Bb = (const short*)Bt + (size_t)(bn + wave * 32 + srow) * K + gchunk * 8;
    const int csw = l15 & 7;

    f32x4 acc[4][4] = {};

    for (int k0 = 0; k0 < K; k0 += 64) {
        __syncthreads();
#pragma unroll
        for (int r8 = 0; r8 < 4; r8++) {
            async16(Ab + k0 + (size_t)(r8 * 8) * K, &As[wave * 32 + r8 * 8][0]);
            async16(Bb + k0 + (size_t)(r8 * 8) * K, &Bs[wave * 32 + r8 * 8][0]);
        }
        __syncthreads();

#pragma unroll
        for (int kk = 0; kk < 2; kk++) {
            s16x8 af[4], bfr[4];
#pragma unroll
            for (int i = 0; i < 4; i++) af[i]  = *(const s16x8*)&As[wm + i * 16 + l15][((kk * 4 + q) ^ csw) * 8];
#pragma unroll
            for (int j = 0; j < 4; j++) bfr[j] = *(const s16x8*)&Bs[wn + j * 16 + l15][((kk * 4 + q) ^ csw) * 8];
#pragma unroll
            for (int i = 0; i < 4; i++)
#pragma unroll
                for (int j = 0; j < 4; j++)
                    acc[i][j] = __builtin_amdgcn_mfma_f32_16x16x32_bf16(af[i], bfr[j], acc[i][j], 0, 0, 0);
        }
    }

#pragma unroll
    for (int i = 0; i < 4; i++) {
#pragma unroll
        for (int j = 0; j < 4; j++) {
            int n = bn + wn + j * 16 + l15;
            float bvv = bias ? __bfloat162float(bias[n]) : 0.f;
#pragma unroll
            for (int r = 0; r < 4; r++) {
                int m = bm + wm + i * 16 + q * 4 + r;
                float v = acc[i][j][r] + bvv;
                if (act) v = gelu_fast(v);
                if (res) v += __bfloat162float(res[(size_t)m * N + n]);
                size_t idx = (size_t)m * N + n;
                if (f32out) ((float*)C)[idx] = v;
                else        ((bf16*)C)[idx]  = __float2bfloat16(v);
            }
        }
    }
}

// ------------------------------ Attention ----------------------------------
// grid (B*H, S/64): dispatch id = stile*32+bh -> id%8 = bh%8, all s-blocks of
// one (b,h) share an XCD; K+V stay L2-resident (round-9 win: FETCH 128->34MB).
// K from fused KVb (col h*64); V from pre-transposed Vt[b][h*64+d][t] (f16).
// Both staged via global_load_lds w16, unpadded [64][64], chunk-permuted.
// Q pre-scaled by 0.125. Post-softmax mask => l is a pure sum.
__global__ __launch_bounds__(256)
void attn_kernel(const bf16* __restrict__ Q, const bf16* __restrict__ KV,
                 const _Float16* __restrict__ Vt, bf16* __restrict__ O)
{
    __shared__ alignas(16) short    Ks[64][64];   // [t][d'], chunk-swizzled
    __shared__ alignas(16) _Float16 Vs[64][64];   // [d][t'], chunk-swizzled

    const int tid  = threadIdx.x;
    const int lane = tid & 63;
    const int wave = tid >> 6;
    const int q    = lane >> 4;
    const int l15  = lane & 15;
    const int bh   = blockIdx.x;                  // XCD key
    const int b    = bh >> 4, h = bh & 15;
    const int sblk   = blockIdx.y * 64;
    const int s_base = sblk + wave * 16;
    const int s_glob = s_base + l15;

    const short* qrow = (const short*)Q + (size_t)(b * 2048 + s_glob) * 1024 + h * 64;
    s16x8 qf0 = *(const s16x8*)(qrow + q * 8);
    s16x8 qf1 = *(const s16x8*)(qrow + 32 + q * 8);

    float l_lane = 0.f;
    f32x4 o_acc[4] = {};

    const int srow = lane >> 3;              // 0..7
    const int gch  = (lane & 7) ^ srow;      // permuted global chunk
    const short*    kbase = (const short*)KV +
        (size_t)(b * 2048 + wave * 16 + srow) * 2048 + h * 64 + gch * 8;
    const _Float16* vbase = Vt +
        (size_t)(b * 1024 + h * 64 + wave * 16 + srow) * 2048 + gch * 8;
    const int key = l15 & 7;                 // frag-read swizzle key

    for (int t0 = 0; t0 < 2048; t0 += 64) {
        const bool needV = (t0 >= sblk);
        const short*    kg = kbase + (size_t)t0 * 2048;
        const _Float16* vg = vbase + t0;
        __syncthreads();
        async16(kg,                    &Ks[wave * 16][0]);
        async16(kg + (size_t)8 * 2048, &Ks[wave * 16 + 8][0]);
        if (needV) {
            async16((const short*)vg,                      (short*)&Vs[wave * 16][0]);
            async16((const short*)(vg + (size_t)8 * 2048), (short*)&Vs[wave * 16 + 8][0]);
        }
        __syncthreads();

#pragma unroll
        for (int sub = 0; sub < 4; sub++) {
            const int tb  = sub * 16;
            const int rel = t0 + tb - s_base;   // wave-uniform
            s16x8 kf0 = *(const s16x8*)&Ks[tb + l15][(q ^ key) * 8];
            s16x8 kf1 = *(const s16x8*)&Ks[tb + l15][((q + 4) ^ key) * 8];
            f32x4 st = {};
            st = __builtin_amdgcn_mfma_f32_16x16x32_bf16(kf0, qf0, st, 0, 0, 0);
            st = __builtin_amdgcn_mfma_f32_16x16x32_bf16(kf1, qf1, st, 0, 0, 0);
            float p[4];
#pragma unroll
            for (int r = 0; r < 4; r++) {
                p[r] = __expf(st[r]);
                l_lane += p[r];
            }
            if (rel >= 0) {
                h16x4 pf;
                if (rel == 0) {
#pragma unroll
                    for (int r = 0; r < 4; r++)
                        pf[r] = (q * 4 + r > l15) ? (_Float16)p[r] : (_Float16)0.f;
                } else {
#pragma unroll
                    for (int r = 0; r < 4; r++) pf[r] = (_Float16)p[r];
                }
#pragma unroll
                for (int dt = 0; dt < 4; dt++) {
                    h16x4 vf = *(const h16x4*)&Vs[dt * 16 + l15]
                        [(((2 * sub + (q >> 1)) ^ key) * 8) + (q & 1) * 4];
                    o_acc[dt] = __builtin_amdgcn_mfma_f32_16x16x16f16(pf, vf, o_acc[dt], 0, 0, 0);
                }
            }
        }
    }

    float l = l_lane;
    l += __shfl_xor(l, 16, 64);
    l += __shfl_xor(l, 32, 64);
    float linv[4];
#pragma unroll
    for (int r = 0; r < 4; r++) linv[r] = 1.f / __shfl(l, q * 4 + r, 64);
#pragma unroll
    for (int dt = 0; dt < 4; dt++)
#pragma unroll
        for (int r = 0; r < 4; r++) {
            int s = s_base + q * 4 + r;
            int d = dt * 16 + l15;
            O[(size_t)(b * 2048 + s) * 1024 + h * 64 + d] =
                __float2bfloat16(o_acc[dt][r] * linv[r]);
        }
}

// ------------------------------- launcher ----------------------------------
extern "C" void kernel_launch(void* const* d_in, const int* in_sizes, int n_in,
                              void* d_out, int out_size, void* d_ws, size_t ws_size,
                              hipStream_t stream)
{
    const void* x     = d_in[0];
    const void* y     = d_in[1];
    const void* Wq    = d_in[2];
    const void* Wk    = d_in[3];
    const void* Wv    = d_in[4];
    const void* li1_w = d_in[5];
    const void* li1_b = d_in[6];
    const void* ln1_w = d_in[7];
    const void* ln1_b = d_in[8];
    const void* ln2_w = d_in[9];
    const void* ln2_b = d_in[10];
    const void* ln3_w = d_in[11];
    const void* ln3_b = d_in[12];
    const void* li2_w = d_in[13];
    const void* li2_b = d_in[14];
    const void* li3_w = d_in[15];
    const void* li3_b = d_in[16];

    char* w = (char*)d_ws;
    const size_t MB = 1u << 20;
    bf16* xn    = (bf16*)(w + 0 * MB);
    bf16* yn    = (bf16*)(w + 8 * MB);
    bf16* WqT   = (bf16*)(w + 16 * MB);
    bf16* WkT   = (bf16*)(w + 18 * MB);   // WkT+WvT contiguous = fused KV weights
    bf16* WvT   = (bf16*)(w + 20 * MB);
    bf16* li1T  = (bf16*)(w + 22 * MB);
    bf16* li2T  = (bf16*)(w + 24 * MB);
    bf16* li3T  = (bf16*)(w + 32 * MB);
    bf16* xout  = (bf16*)(w + 40 * MB);
    bf16* Qb    = (bf16*)(w + 48 * MB);
    bf16* KVb   = (bf16*)(w + 56 * MB);   // [4096][2048], 16MB
    _Float16* Vt = (_Float16*)(w + 72 * MB); // [2][1024][2048] f16, 8MB
    bf16* h2    = (bf16*)(w + 48 * MB);   // reuses Qb/KVb/Vt after attention
    bf16* xc    = (bf16*)(w + 80 * MB);   // canonical bf16 copy of x (residual)
    int*  flag  = (int*) (w + 88 * MB);
    bf16* li1bc = (bf16*)(w + 88 * MB + 4096);
    bf16* li2bc = (bf16*)(w + 88 * MB + 8192);
    bf16* li3bc = (bf16*)(w + 88 * MB + 24576);
    bf16* Ob    = yn;                     // reuse yn after KV projection
    bf16* hn    = xn;                     // reuse xn after Q projection

    // 0. dtype detection (deterministic per input -> graph-safe)
    detect_dtype<<<1, 256, 0, stream>>>((const short*)x, flag);

    // 1. biases (single launch)
    conv_bias3<<<24, 256, 0, stream>>>(li1_b, li2_b, li3_b, li1bc, li2bc, li3bc, flag);

    // 2. LayerNorms (LN1 also emits the canonical bf16 copy of x)
    ln_kernel<<<4096, 256, 0, stream>>>(x, ln1_w, ln1_b, xn, flag, 0, xc);
    ln_kernel<<<4096, 256, 0, stream>>>(y, ln2_w, ln2_b, yn, flag, 0, nullptr);

    // 3. weight re-layouts (LDS-tiled, coalesced)
    pack_qkv_tiled<<<dim3(2, 32, 16), 256, 0, stream>>>(Wq, WqT, flag);
    pack_qkv_tiled<<<dim3(2, 32, 16), 256, 0, stream>>>(Wk, WkT, flag);
    pack_qkv_tiled<<<dim3(2, 32, 16), 256, 0, stream>>>(Wv, WvT, flag);
    transpose_tiled<<<dim3(32, 32),  256, 0, stream>>>(li1_w, li1T, 1024, 1024, flag);
    transpose_tiled<<<dim3(128, 32), 256, 0, stream>>>(li2_w, li2T, 1024, 4096, flag);
    transpose_tiled<<<dim3(32, 128), 256, 0, stream>>>(li3_w, li3T, 4096, 1024, flag);

    // 4. projections: Q (pre-scaled by 1/8) and fused KV, then V -> Vt (f16)
    gemm_bt64<2><<<dim3(32, 16), 256, 0, stream>>>(xn, WqT, nullptr, nullptr, Qb, 4096, 1024, 1024, 0, flag, 0, 0.125f);
    gemm_bt64<1><<<dim3(32, 32), 256, 0, stream>>>(yn, WkT, nullptr, nullptr, KVb, 4096, 2048, 1024, 0, flag, 0, 1.0f);
    v_transpose<<<dim3(64, 32, 2), 256, 0, stream>>>(KVb, Vt);

    // 5. attention -> O [B,S,H*D]   (grid x=bh for XCD locality)
    attn_kernel<<<dim3(32, 32), 256, 0, stream>>>(Qb, KVb, Vt, Ob);

    // 6. x_out = x + O @ li1_w + li1_b
    gemm_bt64<2><<<dim3(32, 16), 256, 0, stream>>>(Ob, li1T, li1bc, xc, xout, 4096, 1024, 1024, 0, flag, 0, 1.0f);

    // 7. hn = LN3(x_out)
    ln_kernel<<<4096, 256, 0, stream>>>(xout, ln3_w, ln3_b, hn, flag, 1, nullptr);

    // 8. h2 = gelu(hn @ li2_w + li2_b)   (fast tanh-form GELU)
    gemm_bt128<<<dim3(32, 32), 256, 0, stream>>>(hn, li2T, li2bc, nullptr, h2, 4096, 4096, 1024, 1, flag, 0);

    // 9. out = x_out + h2 @ li3_w + li3_b   (dtype-matched store)
    gemm_bt64<2><<<dim3(32, 16), 256, 0, stream>>>(h2, li3T, li3bc, xout, d_out, 4096, 1024, 4096, 0, flag, 1, 1.0f);
}